// Round 4
// baseline (10605.658 us; speedup 1.0000x reference)
//
#include <hip/hip_runtime.h>
#include <math.h>

#define NB   32    // batch
#define TH   128   // scan steps
#define NL   6     // layers
#define DD   128   // model dim
#define NH   4     // heads
#define DHD  32    // head dim
#define TCAP 128   // max cached tokens
#define D3   384
#define D4   512

typedef _Float16 f16;
typedef _Float16 f16x8 __attribute__((ext_vector_type(8)));

// fp32 -> fp16 (RNE) weight conversion into workspace
__global__ void prep_kernel(const float* __restrict__ qkv, const float* __restrict__ proj,
                            const float* __restrict__ fc,  const float* __restrict__ fc2,
                            f16* __restrict__ out) {
    int i = blockIdx.x * blockDim.x + threadIdx.x;
    const int n0 = NL * DD * D3, n1 = NL * DD * DD, n2 = NL * DD * D4, n3 = NL * D4 * DD;
    const int total = n0 + n1 + n2 + n3;
    if (i >= total) return;
    float v;
    if (i < n0)                 v = qkv[i];
    else if (i < n0 + n1)       v = proj[i - n0];
    else if (i < n0 + n1 + n2)  v = fc[i - n0 - n1];
    else                        v = fc2[i - n0 - n1 - n2];
    out[i] = (f16)v;
}

__device__ __forceinline__ float wave_xor_sum(float v) {
    #pragma unroll
    for (int off = 1; off < 64; off <<= 1) v += __shfl_xor(v, off);
    return v;
}
__device__ __forceinline__ float wave_xor_max(float v) {
    #pragma unroll
    for (int off = 1; off < 64; off <<= 1) v = fmaxf(v, __shfl_xor(v, off));
    return v;
}
__device__ __forceinline__ float gelu_tanh(float v) {
    float t = v * v * v;
    return 0.5f * v * (1.f + tanhf(0.7978845608028654f * (v + 0.044715f * t)));
}

// Counted-vmcnt barrier: drain LDS only, let global (prefetch) loads stay in
// flight across the barrier. hipcc's __syncthreads emits s_waitcnt vmcnt(0)
// which serialized every phase's weight prefetch into the barrier (R3: 2.46us
// per phase vs ~0.35us of chain work). asm memory clobbers bracket the
// barrier so no memory op is compiler-moved across it.
__device__ __forceinline__ void bar_lds() {
    asm volatile("s_waitcnt lgkmcnt(0)" ::: "memory");
    __builtin_amdgcn_s_barrier();
    asm volatile("" ::: "memory");
}
// Step-boundary barrier: additionally drain vmcnt so this step's global K/V
// stores are visible to step i+1's clamped K/V reads (one full drain per
// step instead of 31).
__device__ __forceinline__ void bar_step() {
    asm volatile("s_waitcnt vmcnt(0) lgkmcnt(0)" ::: "memory");
    __builtin_amdgcn_s_barrier();
    asm volatile("" ::: "memory");
}

// One workgroup (512 threads) per batch element; 128 KV-cached decode steps.
// 5 raw-barrier phases per layer (A:qkv+LN1, B:attn, C:proj, D:fc+LN2, E:fc2).
// Weight tiles prefetched into registers one phase ahead; with lgkm-only
// barriers the prefetch streams DURING the next phase instead of draining at
// the barrier. K/V row i passes through LDS (kvK/kvV) within the step; global
// K/V reads touch only rows <= i-1 (visible since the previous bar_step).
__global__ __launch_bounds__(512) __attribute__((amdgpu_waves_per_eu(2, 2))) void gpt_loop(
    const float* __restrict__ data,  const float* __restrict__ r,
    const float* __restrict__ wte_w, const float* __restrict__ wte_b,
    const float* __restrict__ wpe,
    const float* __restrict__ ln1_w, const float* __restrict__ ln1_b,
    const float* __restrict__ ln2_w, const float* __restrict__ ln2_b,
    const float* __restrict__ qkv_b, const float* __restrict__ proj_b,
    const float* __restrict__ fc_b,  const float* __restrict__ fc2_b,
    const float* __restrict__ lnf_w, const float* __restrict__ lnf_b,
    const float* __restrict__ head_w,const float* __restrict__ head_b,
    const f16* __restrict__ Wq, const f16* __restrict__ Wp,
    const f16* __restrict__ Wf, const f16* __restrict__ Wf2,
    f16* __restrict__ Kc, f16* __restrict__ Vc,
    float* __restrict__ Y)
{
    const int b    = blockIdx.x;
    const int tid  = threadIdx.x;
    const int lane = tid & 63;
    const int wid  = tid >> 6;

    __shared__ __align__(16) float x[DD], qv[DD], o[DD], hmid[D4];
    __shared__ __align__(16) float sc[NH][TCAP];
    __shared__ __align__(16) f16 kvK[DD], kvV[DD];   // current-step K/V row (LDS bypass)
    __shared__ __align__(16) float c_ln1w[NL][DD], c_ln1b[NL][DD], c_ln2w[NL][DD], c_ln2b[NL][DD];
    __shared__ __align__(16) float c_qkvb[NL][D3], c_projb[NL][DD], c_fcb[NL][D4], c_fc2b[NL][DD];
    __shared__ __align__(16) float c_lnfw[DD], c_lnfb[DD], c_headw[DD], c_wte0[DD], c_wte1[DD], c_wteb[DD];

    const float p0 = data[b * 2 + 0];
    const float p1 = data[b * 2 + 1];
    const float hb = head_b[0];

    f16* Kb = Kc + (size_t)b * NL * TCAP * DD;
    f16* Vb = Vc + (size_t)b * NL * TCAP * DD;

    for (int idx = tid; idx < NL * DD; idx += 512) {
        int l = idx / DD, d = idx % DD;
        c_ln1w[l][d] = ln1_w[idx]; c_ln1b[l][d] = ln1_b[idx];
        c_ln2w[l][d] = ln2_w[idx]; c_ln2b[l][d] = ln2_b[idx];
        c_projb[l][d] = proj_b[idx]; c_fc2b[l][d] = fc2_b[idx];
    }
    for (int idx = tid; idx < NL * D3; idx += 512) c_qkvb[idx / D3][idx % D3] = qkv_b[idx];
    for (int idx = tid; idx < NL * D4; idx += 512) c_fcb[idx / D4][idx % D4] = fc_b[idx];
    if (tid < DD) {
        c_lnfw[tid] = lnf_w[tid]; c_lnfb[tid] = lnf_b[tid]; c_headw[tid] = head_w[tid];
        c_wte0[tid] = wte_w[tid]; c_wte1[tid] = wte_w[DD + tid]; c_wteb[tid] = wte_b[tid];
    }
    __syncthreads();

    // ---- prologue: state + x-init for step 0 + wq(layer 0) prefetch ----
    float s_reg = 0.f;                       // state lives in wave-0 registers
    if (wid == 0) {
        float e0 = r[b * TH + 0];            // s=0, u=0 at step 0
        x[lane]      = e0 * c_wte0[lane]      + c_wteb[lane]      + wpe[lane];
        x[lane + 64] = e0 * c_wte0[lane + 64] + c_wteb[lane + 64] + wpe[64 + lane];
    }

    const int cgq = lane & 7, ksq = lane >> 3;       // qkv/fc mapping: 8 cols x 8 k-splits
    const int cbq = wid * 64 + cgq * 8, k0q = ksq * 16;
    const int cg2 = lane & 1, ks2 = lane >> 1;       // proj/fc2 mapping
    const int cb2 = (wid * 2 + cg2) * 8;
    const int hh  = wid - 4;                          // head for waves 4..7
    const int vcg = lane & 3, vjs = lane >> 2;        // AV mapping: 4 col-groups x 16 j-splits

    f16x8 wq[16];
    if (wid < 6) {
        const f16* W = Wq + cbq;
        #pragma unroll
        for (int k = 0; k < 16; k++) wq[k] = *(const f16x8*)(W + (size_t)(k0q + k) * D3);
    }
    __syncthreads();

    for (int i = 0; i < TH; i++) {
        // step-top prefetches for the head/x-init phase (held in regs all step)
        const int inext = (i + 1 < TH) ? (i + 1) : (TH - 1);
        float r_next = r[b * TH + inext];
        float wpe_a  = wpe[(i + 1) * DD + lane];
        float wpe_b  = wpe[(i + 1) * DD + 64 + lane];

        for (int l = 0; l < NL; l++) {
            f16* Krow = Kb + ((size_t)l * TCAP + i) * DD;
            f16* Vrow = Vb + ((size_t)l * TCAP + i) * DD;
            const f16* Kl = Kb + (size_t)l * TCAP * DD;
            const f16* Vl = Vb + (size_t)l * TCAP * DD;

            f16x8 wp4[4];      // consumed in C
            f16x8 wf[16];      // consumed in D
            f16x8 wf2[16];     // consumed in E

            // ================= Phase A: LN1(inline) + qkv =================
            if (wid < 6) {
                float v0 = x[lane], v1 = x[lane + 64];
                float sm = wave_xor_sum(v0 + v1);
                float sq = wave_xor_sum(v0 * v0 + v1 * v1);
                float m  = sm * (1.f / DD);
                float rs = rsqrtf(sq * (1.f / DD) - m * m + 1e-5f);
                float hk[16];
                #pragma unroll
                for (int t = 0; t < 4; t++) {
                    float4 xx = *(const float4*)&x[k0q + 4 * t];
                    float4 ww = *(const float4*)&c_ln1w[l][k0q + 4 * t];
                    float4 bb = *(const float4*)&c_ln1b[l][k0q + 4 * t];
                    hk[4 * t + 0] = (xx.x - m) * rs * ww.x + bb.x;
                    hk[4 * t + 1] = (xx.y - m) * rs * ww.y + bb.y;
                    hk[4 * t + 2] = (xx.z - m) * rs * ww.z + bb.z;
                    hk[4 * t + 3] = (xx.w - m) * rs * ww.w + bb.w;
                }
                float acc[8] = {0.f,0.f,0.f,0.f,0.f,0.f,0.f,0.f};
                #pragma unroll
                for (int k = 0; k < 16; k++) {
                    f16x8 w = wq[k];
                    float hkk = hk[k];
                    #pragma unroll
                    for (int j = 0; j < 8; j++) acc[j] += hkk * (float)w[j];
                }
                #pragma unroll
                for (int off = 8; off <= 32; off <<= 1) {
                    #pragma unroll
                    for (int j = 0; j < 8; j++) acc[j] += __shfl_xor(acc[j], off);
                }
                if (ksq == 0) {
                    if (cbq < DD) {
                        #pragma unroll
                        for (int j = 0; j < 8; j++) qv[cbq + j] = acc[j] + c_qkvb[l][cbq + j];
                    } else if (cbq < 2 * DD) {
                        f16x8 kv;
                        #pragma unroll
                        for (int j = 0; j < 8; j++) kv[j] = (f16)(acc[j] + c_qkvb[l][cbq + j]);
                        *(f16x8*)(Krow + (cbq - DD)) = kv;        // for future steps
                        *(f16x8*)(&kvK[cbq - DD])   = kv;        // for THIS step (LDS)
                    } else {
                        f16x8 vv;
                        #pragma unroll
                        for (int j = 0; j < 8; j++) vv[j] = (f16)(acc[j] + c_qkvb[l][cbq + j]);
                        *(f16x8*)(Vrow + (cbq - 2 * DD)) = vv;
                        *(f16x8*)(&kvV[cbq - 2 * DD])   = vv;
                    }
                }
            }
            bar_lds();

            // ===== Phase B: attn (waves 4..7); waves 0..3 prefetch wp4+wf ==
            if (wid < 4) {
                const f16* W = Wp + (size_t)l * DD * DD + cb2;
                #pragma unroll
                for (int k = 0; k < 4; k++) wp4[k] = *(const f16x8*)(W + (size_t)(ks2 * 4 + k) * DD);
                const f16* W2 = Wf + (size_t)l * DD * D4 + cbq;
                #pragma unroll
                for (int k = 0; k < 16; k++) wf[k] = *(const f16x8*)(W2 + (size_t)(k0q + k) * D4);
            } else {
                // global K/V reads touch rows <= i-1 only (stable since last
                // bar_step); row i comes from LDS kvK/kvV.
                const int im1 = (i > 0) ? (i - 1) : 0;
                const int j0 = (lane < i) ? lane : im1;
                const int j1 = (lane + 64 < i) ? (lane + 64) : im1;
                const f16* K0p = Kl + (size_t)j0 * DD + hh * DHD;
                const f16* K1p = Kl + (size_t)j1 * DD + hh * DHD;
                f16x8 kr0[4], kr1[4], kfr[4];
                #pragma unroll
                for (int g = 0; g < 4; g++) {
                    kr0[g] = *(const f16x8*)(K0p + g * 8);
                    kr1[g] = *(const f16x8*)(K1p + g * 8);
                }
                f16x8 vreg[8];
                const f16* Vp = Vl + hh * DHD + vcg * 8;
                #pragma unroll
                for (int t = 0; t < 8; t++) {
                    int row = vjs * 8 + t; row = (row < i) ? row : im1;
                    vreg[t] = *(const f16x8*)(Vp + (size_t)row * DD);
                }
                #pragma unroll
                for (int g = 0; g < 4; g++) kfr[g] = *(const f16x8*)(&kvK[hh * DHD + g * 8]);
                f16x8 vi = *(const f16x8*)(&kvV[hh * DHD + vcg * 8]);

                const bool ok0 = (lane <= i), ok1 = (lane + 64 <= i);
                float d0 = 0.f, d1 = 0.f;
                #pragma unroll
                for (int g = 0; g < 4; g++) {
                    f16x8 ka  = (lane      >= i) ? kfr[g] : kr0[g];
                    f16x8 kb2 = (lane + 64 >= i) ? kfr[g] : kr1[g];
                    float4 qa = *(const float4*)&qv[hh * DHD + g * 8];
                    float4 qb = *(const float4*)&qv[hh * DHD + g * 8 + 4];
                    d0 += qa.x*(float)ka[0] + qa.y*(float)ka[1] + qa.z*(float)ka[2] + qa.w*(float)ka[3]
                        + qb.x*(float)ka[4] + qb.y*(float)ka[5] + qb.z*(float)ka[6] + qb.w*(float)ka[7];
                    d1 += qa.x*(float)kb2[0] + qa.y*(float)kb2[1] + qa.z*(float)kb2[2] + qa.w*(float)kb2[3]
                        + qb.x*(float)kb2[4] + qb.y*(float)kb2[5] + qb.z*(float)kb2[6] + qb.w*(float)kb2[7];
                }
                const float sscale = 0.17677669529663687f;
                float s0 = ok0 ? d0 * sscale : -1e30f;
                float s1 = ok1 ? d1 * sscale : -1e30f;
                float mx = wave_xor_max(fmaxf(s0, s1));
                float e0 = ok0 ? expf(s0 - mx) : 0.f;
                float e1 = ok1 ? expf(s1 - mx) : 0.f;
                float inv = 1.f / wave_xor_sum(e0 + e1);
                sc[hh][lane]      = e0 * inv;      // rows > i get exactly 0
                sc[hh][lane + 64] = e1 * inv;
                __builtin_amdgcn_wave_barrier();   // sc write -> read, same wave
                // AV (rows > i have p == 0; row i uses vi)
                const int ja = vjs * 8;
                float4 pa = *(const float4*)&sc[hh][ja];
                float4 pb = *(const float4*)&sc[hh][ja + 4];
                float pv[8] = {pa.x, pa.y, pa.z, pa.w, pb.x, pb.y, pb.z, pb.w};
                float a[8] = {0.f,0.f,0.f,0.f,0.f,0.f,0.f,0.f};
                #pragma unroll
                for (int t = 0; t < 8; t++) {
                    f16x8 vv = (ja + t == i) ? vi : vreg[t];
                    float p = pv[t];
                    #pragma unroll
                    for (int u = 0; u < 8; u++) a[u] += p * (float)vv[u];
                }
                #pragma unroll
                for (int off = 4; off <= 32; off <<= 1) {
                    #pragma unroll
                    for (int u = 0; u < 8; u++) a[u] += __shfl_xor(a[u], off);
                }
                if (vjs == 0) {
                    #pragma unroll
                    for (int u = 0; u < 8; u++) o[hh * DHD + vcg * 8 + u] = a[u];
                }
                // K/V register arrays dead -> now prefetch wp4 (floats across barrier)
                const f16* W = Wp + (size_t)l * DD * DD + cb2;
                #pragma unroll
                for (int k = 0; k < 4; k++) wp4[k] = *(const f16x8*)(W + (size_t)(ks2 * 4 + k) * DD);
            }
            bar_lds();

            // ==== Phase C: proj + residual; attn waves prefetch wf ====
            {
                float4 ov = *(const float4*)&o[ks2 * 4];
                float oo[4] = {ov.x, ov.y, ov.z, ov.w};
                float acc[8] = {0.f,0.f,0.f,0.f,0.f,0.f,0.f,0.f};
                #pragma unroll
                for (int k = 0; k < 4; k++) {
                    f16x8 w = wp4[k];
                    float ok_ = oo[k];
                    #pragma unroll
                    for (int j = 0; j < 8; j++) acc[j] += ok_ * (float)w[j];
                }
                if (wid >= 4) {    // K/V regs dead; attn waves fetch wf here
                    const f16* W2 = Wf + (size_t)l * DD * D4 + cbq;
                    #pragma unroll
                    for (int k = 0; k < 16; k++) wf[k] = *(const f16x8*)(W2 + (size_t)(k0q + k) * D4);
                }
                #pragma unroll
                for (int off = 2; off <= 32; off <<= 1) {
                    #pragma unroll
                    for (int j = 0; j < 8; j++) acc[j] += __shfl_xor(acc[j], off);
                }
                if (ks2 == 0) {
                    #pragma unroll
                    for (int j = 0; j < 8; j++) x[cb2 + j] += acc[j] + c_projb[l][cb2 + j];
                }
            }
            bar_lds();

            // == Phase D: LN2(inline) + fc + gelu; prefetch wf2 after FMA ==
            {
                float v0 = x[lane], v1 = x[lane + 64];
                float sm = wave_xor_sum(v0 + v1);
                float sq = wave_xor_sum(v0 * v0 + v1 * v1);
                float m  = sm * (1.f / DD);
                float rs = rsqrtf(sq * (1.f / DD) - m * m + 1e-5f);
                float hk[16];
                #pragma unroll
                for (int t = 0; t < 4; t++) {
                    float4 xx = *(const float4*)&x[k0q + 4 * t];
                    float4 ww = *(const float4*)&c_ln2w[l][k0q + 4 * t];
                    float4 bb = *(const float4*)&c_ln2b[l][k0q + 4 * t];
                    hk[4 * t + 0] = (xx.x - m) * rs * ww.x + bb.x;
                    hk[4 * t + 1] = (xx.y - m) * rs * ww.y + bb.y;
                    hk[4 * t + 2] = (xx.z - m) * rs * ww.z + bb.z;
                    hk[4 * t + 3] = (xx.w - m) * rs * ww.w + bb.w;
                }
                float acc[8] = {0.f,0.f,0.f,0.f,0.f,0.f,0.f,0.f};
                #pragma unroll
                for (int k = 0; k < 16; k++) {
                    f16x8 w = wf[k];
                    float hkk = hk[k];
                    #pragma unroll
                    for (int j = 0; j < 8; j++) acc[j] += hkk * (float)w[j];
                }
                // wf dead -> prefetch wf2 for phase E
                {
                    const f16* W = Wf2 + (size_t)l * D4 * DD + cb2;
                    #pragma unroll
                    for (int k = 0; k < 16; k++) wf2[k] = *(const f16x8*)(W + (size_t)(ks2 * 16 + k) * DD);
                }
                #pragma unroll
                for (int off = 8; off <= 32; off <<= 1) {
                    #pragma unroll
                    for (int j = 0; j < 8; j++) acc[j] += __shfl_xor(acc[j], off);
                }
                if (ksq == 0) {
                    #pragma unroll
                    for (int j = 0; j < 8; j++) hmid[cbq + j] = gelu_tanh(acc[j] + c_fcb[l][cbq + j]);
                }
            }
            bar_lds();

            // == Phase E: fc2 + residual; prefetch wq(next layer) after FMA ==
            {
                float mk[16];
                #pragma unroll
                for (int t = 0; t < 4; t++) {
                    float4 mm = *(const float4*)&hmid[ks2 * 16 + 4 * t];
                    mk[4 * t + 0] = mm.x; mk[4 * t + 1] = mm.y;
                    mk[4 * t + 2] = mm.z; mk[4 * t + 3] = mm.w;
                }
                float acc[8] = {0.f,0.f,0.f,0.f,0.f,0.f,0.f,0.f};
                #pragma unroll
                for (int k = 0; k < 16; k++) {
                    f16x8 w = wf2[k];
                    float mkk = mk[k];
                    #pragma unroll
                    for (int j = 0; j < 8; j++) acc[j] += mkk * (float)w[j];
                }
                // wf2 dead -> prefetch wq for next layer's phase A
                {
                    const int ln = (l + 1 == NL) ? 0 : (l + 1);
                    if (wid < 6) {
                        const f16* W = Wq + (size_t)ln * DD * D3 + cbq;
                        #pragma unroll
                        for (int k = 0; k < 16; k++) wq[k] = *(const f16x8*)(W + (size_t)(k0q + k) * D3);
                    }
                }
                #pragma unroll
                for (int off = 2; off <= 32; off <<= 1) {
                    #pragma unroll
                    for (int j = 0; j < 8; j++) acc[j] += __shfl_xor(acc[j], off);
                }
                if (ks2 == 0) {
                    #pragma unroll
                    for (int j = 0; j < 8; j++) x[cb2 + j] += acc[j] + c_fc2b[l][cb2 + j];
                }
            }
            bar_lds();
        } // layers

        // ==== head + state update + x-init for step i+1 (wave 0 only) ====
        if (wid == 0) {
            float v0 = x[lane], v1 = x[lane + 64];
            float sm = wave_xor_sum(v0 + v1);
            float sq = wave_xor_sum(v0 * v0 + v1 * v1);
            float m  = sm * (1.f / DD);
            float rs = rsqrtf(sq * (1.f / DD) - m * m + 1e-5f);
            float h0 = (v0 - m) * rs * c_lnfw[lane]      + c_lnfb[lane];
            float h1 = (v1 - m) * rs * c_lnfw[lane + 64] + c_lnfb[lane + 64];
            float v  = wave_xor_sum(h0 * c_headw[lane] + h1 * c_headw[lane + 64]);
            float un = v + hb;
            float s  = s_reg;
            if (lane == 0) Y[b * TH + i] = s;
            float sn = s + (-p0 * s + p1 * tanhf(un));
            s_reg = sn;
            float e = r_next - sn;
            x[lane]      = e * c_wte0[lane]      + un * c_wte1[lane]      + c_wteb[lane]      + wpe_a;
            x[lane + 64] = e * c_wte0[lane + 64] + un * c_wte1[lane + 64] + c_wteb[lane + 64] + wpe_b;
        }
        bar_step();   // full vmcnt drain once per step: KV stores -> visible i+1
    } // steps
}

extern "C" void kernel_launch(void* const* d_in, const int* in_sizes, int n_in,
                              void* d_out, int out_size, void* d_ws, size_t ws_size,
                              hipStream_t stream) {
    const float* data   = (const float*)d_in[0];
    const float* r      = (const float*)d_in[1];
    const float* wte_w  = (const float*)d_in[2];
    const float* wte_b  = (const float*)d_in[3];
    const float* wpe    = (const float*)d_in[4];
    const float* ln1_w  = (const float*)d_in[5];
    const float* ln1_b  = (const float*)d_in[6];
    const float* ln2_w  = (const float*)d_in[7];
    const float* ln2_b  = (const float*)d_in[8];
    const float* qkv_w  = (const float*)d_in[9];
    const float* qkv_b  = (const float*)d_in[10];
    const float* proj_w = (const float*)d_in[11];
    const float* proj_b = (const float*)d_in[12];
    const float* fc_w   = (const float*)d_in[13];
    const float* fc_b   = (const float*)d_in[14];
    const float* fc2_w  = (const float*)d_in[15];
    const float* fc2_b  = (const float*)d_in[16];
    const float* lnf_w  = (const float*)d_in[17];
    const float* lnf_b  = (const float*)d_in[18];
    const float* head_w = (const float*)d_in[19];
    const float* head_b = (const float*)d_in[20];

    f16* wsp = (f16*)d_ws;
    f16* Wq  = wsp;
    f16* Wp  = Wq  + NL * DD * D3;
    f16* Wf  = Wp  + NL * DD * DD;
    f16* Wf2 = Wf  + NL * DD * D4;
    f16* Kc  = Wf2 + NL * D4 * DD;
    f16* Vc  = Kc  + (size_t)NB * NL * TCAP * DD;

    const int n_w = NL * DD * D3 + NL * DD * DD + NL * DD * D4 + NL * D4 * DD;
    prep_kernel<<<(n_w + 255) / 256, 256, 0, stream>>>(qkv_w, proj_w, fc_w, fc2_w, Wq);

    gpt_loop<<<NB, 512, 0, stream>>>(
        data, r, wte_w, wte_b, wpe, ln1_w, ln1_b, ln2_w, ln2_b,
        qkv_b, proj_b, fc_b, fc2_b, lnf_w, lnf_b, head_w, head_b,
        Wq, Wp, Wf, Wf2, Kc, Vc, (float*)d_out);
}

// Round 5
// 8949.567 us; speedup vs baseline: 1.1850x; 1.1850x over previous
//
#include <hip/hip_runtime.h>
#include <math.h>

#define NB   32    // batch
#define TH   128   // scan steps
#define NL   6     // layers
#define DD   128   // model dim
#define NH   4     // heads
#define DHD  32    // head dim
#define TCAP 128   // max cached tokens
#define D3   384
#define D4   512

typedef _Float16 f16;
typedef _Float16 f16x8 __attribute__((ext_vector_type(8)));

// fp32 -> fp16 (RNE) weight conversion into workspace
__global__ void prep_kernel(const float* __restrict__ qkv, const float* __restrict__ proj,
                            const float* __restrict__ fc,  const float* __restrict__ fc2,
                            f16* __restrict__ out) {
    int i = blockIdx.x * blockDim.x + threadIdx.x;
    const int n0 = NL * DD * D3, n1 = NL * DD * DD, n2 = NL * DD * D4, n3 = NL * D4 * DD;
    const int total = n0 + n1 + n2 + n3;
    if (i >= total) return;
    float v;
    if (i < n0)                 v = qkv[i];
    else if (i < n0 + n1)       v = proj[i - n0];
    else if (i < n0 + n1 + n2)  v = fc[i - n0 - n1];
    else                        v = fc2[i - n0 - n1 - n2];
    out[i] = (f16)v;
}

__device__ __forceinline__ float wave_xor_sum(float v) {
    #pragma unroll
    for (int off = 1; off < 64; off <<= 1) v += __shfl_xor(v, off);
    return v;
}
__device__ __forceinline__ float wave_xor_max(float v) {
    #pragma unroll
    for (int off = 1; off < 64; off <<= 1) v = fmaxf(v, __shfl_xor(v, off));
    return v;
}
__device__ __forceinline__ float gelu_tanh(float v) {
    float t = v * v * v;
    return 0.5f * v * (1.f + tanhf(0.7978845608028654f * (v + 0.044715f * t)));
}

// lgkm-only barrier: orders all LDS traffic across the barrier but lets
// global (weight-prefetch) loads stay in flight; the compiler's own counted
// s_waitcnt-before-use handles their arrival. asm memory clobbers pin
// compile-time ordering around the barrier.
__device__ __forceinline__ void bar_lds() {
    asm volatile("s_waitcnt lgkmcnt(0)" ::: "memory");
    __builtin_amdgcn_s_barrier();
    asm volatile("" ::: "memory");
}
// Step-boundary barrier: full drain so this step's global K/V stores are
// visible to the next step's clamped (row <= i-1) K/V reads.
__device__ __forceinline__ void bar_step() {
    asm volatile("s_waitcnt vmcnt(0) lgkmcnt(0)" ::: "memory");
    __builtin_amdgcn_s_barrier();
    asm volatile("" ::: "memory");
}

// One workgroup (512 threads) per batch element; 128 KV-cached decode steps.
// 5 lgkm-barrier phases/layer (A:qkv+LN1, B:attn, C:proj, D:fc+LN2, E:fc2).
// Weight tiles prefetched one phase ahead in HALF-TILES (32 regs each),
// each issued exactly where the previous array dies, so no array lives
// more than one barrier (except wq E->A and 16-reg wp4 A->C). Peak
// liveness ~115 VGPRs -> no spill even at the 128-reg cap (R4's spill:
// WRITE_SIZE 153 MB came from wf living 3 phases).
__global__ __launch_bounds__(512, 1) void gpt_loop(
    const float* __restrict__ data,  const float* __restrict__ r,
    const float* __restrict__ wte_w, const float* __restrict__ wte_b,
    const float* __restrict__ wpe,
    const float* __restrict__ ln1_w, const float* __restrict__ ln1_b,
    const float* __restrict__ ln2_w, const float* __restrict__ ln2_b,
    const float* __restrict__ qkv_b, const float* __restrict__ proj_b,
    const float* __restrict__ fc_b,  const float* __restrict__ fc2_b,
    const float* __restrict__ lnf_w, const float* __restrict__ lnf_b,
    const float* __restrict__ head_w,const float* __restrict__ head_b,
    const f16* __restrict__ Wq, const f16* __restrict__ Wp,
    const f16* __restrict__ Wf, const f16* __restrict__ Wf2,
    f16* __restrict__ Kc, f16* __restrict__ Vc,
    float* __restrict__ Y)
{
    const int b    = blockIdx.x;
    const int tid  = threadIdx.x;
    const int lane = tid & 63;
    const int wid  = tid >> 6;

    __shared__ __align__(16) float x[DD], qv[DD], o[DD], hmid[D4];
    __shared__ __align__(16) float sc[NH][TCAP];
    __shared__ __align__(16) f16 kvK[DD], kvV[DD];   // current-step K/V row (LDS bypass)
    __shared__ __align__(16) float c_ln1w[NL][DD], c_ln1b[NL][DD], c_ln2w[NL][DD], c_ln2b[NL][DD];
    __shared__ __align__(16) float c_qkvb[NL][D3], c_projb[NL][DD], c_fcb[NL][D4], c_fc2b[NL][DD];
    __shared__ __align__(16) float c_lnfw[DD], c_lnfb[DD], c_headw[DD], c_wte0[DD], c_wte1[DD], c_wteb[DD];

    const float p0 = data[b * 2 + 0];
    const float p1 = data[b * 2 + 1];
    const float hb = head_b[0];

    f16* Kb = Kc + (size_t)b * NL * TCAP * DD;
    f16* Vb = Vc + (size_t)b * NL * TCAP * DD;

    for (int idx = tid; idx < NL * DD; idx += 512) {
        int l = idx / DD, d = idx % DD;
        c_ln1w[l][d] = ln1_w[idx]; c_ln1b[l][d] = ln1_b[idx];
        c_ln2w[l][d] = ln2_w[idx]; c_ln2b[l][d] = ln2_b[idx];
        c_projb[l][d] = proj_b[idx]; c_fc2b[l][d] = fc2_b[idx];
    }
    for (int idx = tid; idx < NL * D3; idx += 512) c_qkvb[idx / D3][idx % D3] = qkv_b[idx];
    for (int idx = tid; idx < NL * D4; idx += 512) c_fcb[idx / D4][idx % D4] = fc_b[idx];
    if (tid < DD) {
        c_lnfw[tid] = lnf_w[tid]; c_lnfb[tid] = lnf_b[tid]; c_headw[tid] = head_w[tid];
        c_wte0[tid] = wte_w[tid]; c_wte1[tid] = wte_w[DD + tid]; c_wteb[tid] = wte_b[tid];
    }
    // zero-init this block's KV cache: clamped reads of never-written rows
    // then contribute exact 0 (their softmax weight is 0 anyway).
    {
        float4 z4 = make_float4(0.f, 0.f, 0.f, 0.f);
        float4* K4 = (float4*)Kb; float4* V4 = (float4*)Vb;
        const int n4 = NL * TCAP * DD * 2 / 16;
        for (int idx = tid; idx < n4; idx += 512) { K4[idx] = z4; V4[idx] = z4; }
    }
    __syncthreads();   // full drain: zero-init complete before any KV store/read

    // ---- prologue: state + x-init for step 0 + wq(layer 0) prefetch ----
    float s_reg = 0.f;                       // state lives in wave-0 registers
    if (wid == 0) {
        float e0 = r[b * TH + 0];            // s=0, u=0 at step 0
        x[lane]      = e0 * c_wte0[lane]      + c_wteb[lane]      + wpe[lane];
        x[lane + 64] = e0 * c_wte0[lane + 64] + c_wteb[lane + 64] + wpe[64 + lane];
    }

    const int cgq = lane & 7, ksq = lane >> 3;       // qkv/fc mapping: 8 cols x 8 k-splits
    const int cbq = wid * 64 + cgq * 8, k0q = ksq * 16;
    const int cg2 = lane & 1, ks2 = lane >> 1;       // proj/fc2 mapping
    const int cb2 = (wid * 2 + cg2) * 8;
    const int hh  = wid - 4;                          // head for waves 4..7
    const int vcg = lane & 3, vjs = lane >> 2;        // AV mapping: 4 col-groups x 16 j-splits

    f16x8 wq[16];                                     // persistent: filled in E, used in A
    if (wid < 6) {
        const f16* W = Wq + cbq;
        #pragma unroll
        for (int k = 0; k < 16; k++) wq[k] = *(const f16x8*)(W + (size_t)(k0q + k) * D3);
    }
    __syncthreads();

    for (int i = 0; i < TH; i++) {
        // step-top prefetches for the head/x-init phase (held in regs all step)
        const int inext = (i + 1 < TH) ? (i + 1) : (TH - 1);
        float r_next = r[b * TH + inext];
        float wpe_a  = wpe[(i + 1) * DD + lane];
        float wpe_b  = wpe[(i + 1) * DD + 64 + lane];

        for (int l = 0; l < NL; l++) {
            f16* Krow = Kb + ((size_t)l * TCAP + i) * DD;
            f16* Vrow = Vb + ((size_t)l * TCAP + i) * DD;
            const f16* Kl = Kb + (size_t)l * TCAP * DD;
            const f16* Vl = Vb + (size_t)l * TCAP * DD;

            f16x8 wp4[4];                    // issued end-A, consumed C
            f16x8 wfh1[8], wfh2[8];          // issued end-B / mid-C, consumed D
            f16x8 wf2h1[8], wf2h2[8];        // issued mid-D, consumed E

            // ================= Phase A: LN1(inline) + qkv =================
            if (wid < 6) {
                float v0 = x[lane], v1 = x[lane + 64];
                float sm = wave_xor_sum(v0 + v1);
                float sq = wave_xor_sum(v0 * v0 + v1 * v1);
                float m  = sm * (1.f / DD);
                float rs = rsqrtf(sq * (1.f / DD) - m * m + 1e-5f);
                float hk[16];
                #pragma unroll
                for (int t = 0; t < 4; t++) {
                    float4 xx = *(const float4*)&x[k0q + 4 * t];
                    float4 ww = *(const float4*)&c_ln1w[l][k0q + 4 * t];
                    float4 bb = *(const float4*)&c_ln1b[l][k0q + 4 * t];
                    hk[4 * t + 0] = (xx.x - m) * rs * ww.x + bb.x;
                    hk[4 * t + 1] = (xx.y - m) * rs * ww.y + bb.y;
                    hk[4 * t + 2] = (xx.z - m) * rs * ww.z + bb.z;
                    hk[4 * t + 3] = (xx.w - m) * rs * ww.w + bb.w;
                }
                float acc[8] = {0.f,0.f,0.f,0.f,0.f,0.f,0.f,0.f};
                #pragma unroll
                for (int k = 0; k < 16; k++) {
                    f16x8 w = wq[k];
                    float hkk = hk[k];
                    #pragma unroll
                    for (int j = 0; j < 8; j++) acc[j] += hkk * (float)w[j];
                }
                #pragma unroll
                for (int off = 8; off <= 32; off <<= 1) {
                    #pragma unroll
                    for (int j = 0; j < 8; j++) acc[j] += __shfl_xor(acc[j], off);
                }
                if (ksq == 0) {
                    if (cbq < DD) {
                        #pragma unroll
                        for (int j = 0; j < 8; j++) qv[cbq + j] = acc[j] + c_qkvb[l][cbq + j];
                    } else if (cbq < 2 * DD) {
                        f16x8 kv;
                        #pragma unroll
                        for (int j = 0; j < 8; j++) kv[j] = (f16)(acc[j] + c_qkvb[l][cbq + j]);
                        *(f16x8*)(Krow + (cbq - DD)) = kv;        // for future steps
                        *(f16x8*)(&kvK[cbq - DD])   = kv;        // for THIS step (LDS)
                    } else {
                        f16x8 vv;
                        #pragma unroll
                        for (int j = 0; j < 8; j++) vv[j] = (f16)(acc[j] + c_qkvb[l][cbq + j]);
                        *(f16x8*)(Vrow + (cbq - 2 * DD)) = vv;
                        *(f16x8*)(&kvV[cbq - 2 * DD])   = vv;
                    }
                }
            }
            // wq dead -> issue wp4 for phase C (16 regs, floats across B)
            {
                const f16* W = Wp + (size_t)l * DD * DD + cb2;
                #pragma unroll
                for (int k = 0; k < 4; k++) wp4[k] = *(const f16x8*)(W + (size_t)(ks2 * 4 + k) * DD);
            }
            bar_lds();

            // ========= Phase B: attn (waves 4..7), K/V in-phase ==========
            if (wid >= 4) {
                // global K/V: rows <= i-1 only (stable since last bar_step);
                // row i comes from LDS kvK/kvV.
                const int im1 = (i > 0) ? (i - 1) : 0;
                const int j0 = (lane < i) ? lane : im1;
                const int j1 = (lane + 64 < i) ? (lane + 64) : im1;
                const f16* K0p = Kl + (size_t)j0 * DD + hh * DHD;
                const f16* K1p = Kl + (size_t)j1 * DD + hh * DHD;
                f16x8 kr0[4], kr1[4], kfr[4];
                #pragma unroll
                for (int g = 0; g < 4; g++) {
                    kr0[g] = *(const f16x8*)(K0p + g * 8);
                    kr1[g] = *(const f16x8*)(K1p + g * 8);
                }
                f16x8 vreg[8];
                const f16* Vp = Vl + hh * DHD + vcg * 8;
                #pragma unroll
                for (int t = 0; t < 8; t++) {
                    int row = vjs * 8 + t; row = (row < i) ? row : im1;
                    vreg[t] = *(const f16x8*)(Vp + (size_t)row * DD);
                }
                #pragma unroll
                for (int g = 0; g < 4; g++) kfr[g] = *(const f16x8*)(&kvK[hh * DHD + g * 8]);
                f16x8 vi = *(const f16x8*)(&kvV[hh * DHD + vcg * 8]);

                const bool ok0 = (lane <= i), ok1 = (lane + 64 <= i);
                float d0 = 0.f, d1 = 0.f;
                #pragma unroll
                for (int g = 0; g < 4; g++) {
                    f16x8 ka  = (lane      >= i) ? kfr[g] : kr0[g];
                    f16x8 kb2 = (lane + 64 >= i) ? kfr[g] : kr1[g];
                    float4 qa = *(const float4*)&qv[hh * DHD + g * 8];
                    float4 qb = *(const float4*)&qv[hh * DHD + g * 8 + 4];
                    d0 += qa.x*(float)ka[0] + qa.y*(float)ka[1] + qa.z*(float)ka[2] + qa.w*(float)ka[3]
                        + qb.x*(float)ka[4] + qb.y*(float)ka[5] + qb.z*(float)ka[6] + qb.w*(float)ka[7];
                    d1 += qa.x*(float)kb2[0] + qa.y*(float)kb2[1] + qa.z*(float)kb2[2] + qa.w*(float)kb2[3]
                        + qb.x*(float)kb2[4] + qb.y*(float)kb2[5] + qb.z*(float)kb2[6] + qb.w*(float)kb2[7];
                }
                const float sscale = 0.17677669529663687f;
                float s0 = ok0 ? d0 * sscale : -1e30f;
                float s1 = ok1 ? d1 * sscale : -1e30f;
                float mx = wave_xor_max(fmaxf(s0, s1));
                float e0 = ok0 ? expf(s0 - mx) : 0.f;
                float e1 = ok1 ? expf(s1 - mx) : 0.f;
                float inv = 1.f / wave_xor_sum(e0 + e1);
                sc[hh][lane]      = e0 * inv;      // rows > i get exactly 0
                sc[hh][lane + 64] = e1 * inv;
                __builtin_amdgcn_wave_barrier();   // sc write -> read, same wave
                // AV (rows > i have p == 0; row i uses vi)
                const int ja = vjs * 8;
                float4 pa = *(const float4*)&sc[hh][ja];
                float4 pb = *(const float4*)&sc[hh][ja + 4];
                float pv[8] = {pa.x, pa.y, pa.z, pa.w, pb.x, pb.y, pb.z, pb.w};
                float a[8] = {0.f,0.f,0.f,0.f,0.f,0.f,0.f,0.f};
                #pragma unroll
                for (int t = 0; t < 8; t++) {
                    f16x8 vv = (ja + t == i) ? vi : vreg[t];
                    float p = pv[t];
                    #pragma unroll
                    for (int u = 0; u < 8; u++) a[u] += p * (float)vv[u];
                }
                #pragma unroll
                for (int off = 4; off <= 32; off <<= 1) {
                    #pragma unroll
                    for (int u = 0; u < 8; u++) a[u] += __shfl_xor(a[u], off);
                }
                if (vjs == 0) {
                    #pragma unroll
                    for (int u = 0; u < 8; u++) o[hh * DHD + vcg * 8 + u] = a[u];
                }
            }
            // K/V regs dead -> issue wf half 1 for phase D (32 regs)
            {
                const f16* W2 = Wf + (size_t)l * DD * D4 + cbq;
                #pragma unroll
                for (int k = 0; k < 8; k++) wfh1[k] = *(const f16x8*)(W2 + (size_t)(k0q + k) * D4);
            }
            bar_lds();

            // ==== Phase C: proj + residual; issue wf half 2 after FMA ====
            {
                float4 ov = *(const float4*)&o[ks2 * 4];
                float oo[4] = {ov.x, ov.y, ov.z, ov.w};
                float acc[8] = {0.f,0.f,0.f,0.f,0.f,0.f,0.f,0.f};
                #pragma unroll
                for (int k = 0; k < 4; k++) {
                    f16x8 w = wp4[k];
                    float ok_ = oo[k];
                    #pragma unroll
                    for (int j = 0; j < 8; j++) acc[j] += ok_ * (float)w[j];
                }
                // wp4 dead -> issue wf half 2
                {
                    const f16* W2 = Wf + (size_t)l * DD * D4 + cbq;
                    #pragma unroll
                    for (int k = 0; k < 8; k++) wfh2[k] = *(const f16x8*)(W2 + (size_t)(k0q + 8 + k) * D4);
                }
                #pragma unroll
                for (int off = 2; off <= 32; off <<= 1) {
                    #pragma unroll
                    for (int j = 0; j < 8; j++) acc[j] += __shfl_xor(acc[j], off);
                }
                if (ks2 == 0) {
                    #pragma unroll
                    for (int j = 0; j < 8; j++) x[cb2 + j] += acc[j] + c_projb[l][cb2 + j];
                }
            }
            bar_lds();

            // == Phase D: LN2(inline) + fc + gelu; wf2 halves as wf dies ==
            {
                float v0 = x[lane], v1 = x[lane + 64];
                float sm = wave_xor_sum(v0 + v1);
                float sq = wave_xor_sum(v0 * v0 + v1 * v1);
                float m  = sm * (1.f / DD);
                float rs = rsqrtf(sq * (1.f / DD) - m * m + 1e-5f);
                float hk[16];
                #pragma unroll
                for (int t = 0; t < 4; t++) {
                    float4 xx = *(const float4*)&x[k0q + 4 * t];
                    float4 ww = *(const float4*)&c_ln2w[l][k0q + 4 * t];
                    float4 bb = *(const float4*)&c_ln2b[l][k0q + 4 * t];
                    hk[4 * t + 0] = (xx.x - m) * rs * ww.x + bb.x;
                    hk[4 * t + 1] = (xx.y - m) * rs * ww.y + bb.y;
                    hk[4 * t + 2] = (xx.z - m) * rs * ww.z + bb.z;
                    hk[4 * t + 3] = (xx.w - m) * rs * ww.w + bb.w;
                }
                float acc[8] = {0.f,0.f,0.f,0.f,0.f,0.f,0.f,0.f};
                #pragma unroll
                for (int k = 0; k < 8; k++) {
                    f16x8 w = wfh1[k];
                    float hkk = hk[k];
                    #pragma unroll
                    for (int j = 0; j < 8; j++) acc[j] += hkk * (float)w[j];
                }
                // wfh1 dead -> issue wf2 half 1
                {
                    const f16* W = Wf2 + (size_t)l * D4 * DD + cb2;
                    #pragma unroll
                    for (int k = 0; k < 8; k++) wf2h1[k] = *(const f16x8*)(W + (size_t)(ks2 * 16 + k) * DD);
                }
                #pragma unroll
                for (int k = 0; k < 8; k++) {
                    f16x8 w = wfh2[k];
                    float hkk = hk[8 + k];
                    #pragma unroll
                    for (int j = 0; j < 8; j++) acc[j] += hkk * (float)w[j];
                }
                // wfh2 dead -> issue wf2 half 2
                {
                    const f16* W = Wf2 + (size_t)l * D4 * DD + cb2;
                    #pragma unroll
                    for (int k = 0; k < 8; k++) wf2h2[k] = *(const f16x8*)(W + (size_t)(ks2 * 16 + 8 + k) * DD);
                }
                #pragma unroll
                for (int off = 8; off <= 32; off <<= 1) {
                    #pragma unroll
                    for (int j = 0; j < 8; j++) acc[j] += __shfl_xor(acc[j], off);
                }
                if (ksq == 0) {
                    #pragma unroll
                    for (int j = 0; j < 8; j++) hmid[cbq + j] = gelu_tanh(acc[j] + c_fcb[l][cbq + j]);
                }
            }
            bar_lds();

            // == Phase E: fc2 + residual; wq' halves as wf2 dies ==
            {
                float mk[16];
                #pragma unroll
                for (int t = 0; t < 4; t++) {
                    float4 mm = *(const float4*)&hmid[ks2 * 16 + 4 * t];
                    mk[4 * t + 0] = mm.x; mk[4 * t + 1] = mm.y;
                    mk[4 * t + 2] = mm.z; mk[4 * t + 3] = mm.w;
                }
                const int ln = (l + 1 == NL) ? 0 : (l + 1);
                float acc[8] = {0.f,0.f,0.f,0.f,0.f,0.f,0.f,0.f};
                #pragma unroll
                for (int k = 0; k < 8; k++) {
                    f16x8 w = wf2h1[k];
                    float mkk = mk[k];
                    #pragma unroll
                    for (int j = 0; j < 8; j++) acc[j] += mkk * (float)w[j];
                }
                // wf2h1 dead -> issue wq' half 1
                if (wid < 6) {
                    const f16* W = Wq + (size_t)ln * DD * D3 + cbq;
                    #pragma unroll
                    for (int k = 0; k < 8; k++) wq[k] = *(const f16x8*)(W + (size_t)(k0q + k) * D3);
                }
                #pragma unroll
                for (int k = 0; k < 8; k++) {
                    f16x8 w = wf2h2[k];
                    float mkk = mk[8 + k];
                    #pragma unroll
                    for (int j = 0; j < 8; j++) acc[j] += mkk * (float)w[j];
                }
                // wf2h2 dead -> issue wq' half 2
                if (wid < 6) {
                    const f16* W = Wq + (size_t)ln * DD * D3 + cbq;
                    #pragma unroll
                    for (int k = 0; k < 8; k++) wq[8 + k] = *(const f16x8*)(W + (size_t)(k0q + 8 + k) * D3);
                }
                #pragma unroll
                for (int off = 2; off <= 32; off <<= 1) {
                    #pragma unroll
                    for (int j = 0; j < 8; j++) acc[j] += __shfl_xor(acc[j], off);
                }
                if (ks2 == 0) {
                    #pragma unroll
                    for (int j = 0; j < 8; j++) x[cb2 + j] += acc[j] + c_fc2b[l][cb2 + j];
                }
            }
            bar_lds();
        } // layers

        // ==== head + state update + x-init for step i+1 (wave 0 only) ====
        if (wid == 0) {
            float v0 = x[lane], v1 = x[lane + 64];
            float sm = wave_xor_sum(v0 + v1);
            float sq = wave_xor_sum(v0 * v0 + v1 * v1);
            float m  = sm * (1.f / DD);
            float rs = rsqrtf(sq * (1.f / DD) - m * m + 1e-5f);
            float h0 = (v0 - m) * rs * c_lnfw[lane]      + c_lnfb[lane];
            float h1 = (v1 - m) * rs * c_lnfw[lane + 64] + c_lnfb[lane + 64];
            float v  = wave_xor_sum(h0 * c_headw[lane] + h1 * c_headw[lane + 64]);
            float un = v + hb;
            float s  = s_reg;
            if (lane == 0) Y[b * TH + i] = s;
            float sn = s + (-p0 * s + p1 * tanhf(un));
            s_reg = sn;
            float e = r_next - sn;
            x[lane]      = e * c_wte0[lane]      + un * c_wte1[lane]      + c_wteb[lane]      + wpe_a;
            x[lane + 64] = e * c_wte0[lane + 64] + un * c_wte1[lane + 64] + c_wteb[lane + 64] + wpe_b;
        }
        bar_step();   // full vmcnt drain once per step: KV stores -> visible i+1
    } // steps
}

extern "C" void kernel_launch(void* const* d_in, const int* in_sizes, int n_in,
                              void* d_out, int out_size, void* d_ws, size_t ws_size,
                              hipStream_t stream) {
    const float* data   = (const float*)d_in[0];
    const float* r      = (const float*)d_in[1];
    const float* wte_w  = (const float*)d_in[2];
    const float* wte_b  = (const float*)d_in[3];
    const float* wpe    = (const float*)d_in[4];
    const float* ln1_w  = (const float*)d_in[5];
    const float* ln1_b  = (const float*)d_in[6];
    const float* ln2_w  = (const float*)d_in[7];
    const float* ln2_b  = (const float*)d_in[8];
    const float* qkv_w  = (const float*)d_in[9];
    const float* qkv_b  = (const float*)d_in[10];
    const float* proj_w = (const float*)d_in[11];
    const float* proj_b = (const float*)d_in[12];
    const float* fc_w   = (const float*)d_in[13];
    const float* fc_b   = (const float*)d_in[14];
    const float* fc2_w  = (const float*)d_in[15];
    const float* fc2_b  = (const float*)d_in[16];
    const float* lnf_w  = (const float*)d_in[17];
    const float* lnf_b  = (const float*)d_in[18];
    const float* head_w = (const float*)d_in[19];
    const float* head_b = (const float*)d_in[20];

    f16* wsp = (f16*)d_ws;
    f16* Wq  = wsp;
    f16* Wp  = Wq  + NL * DD * D3;
    f16* Wf  = Wp  + NL * DD * DD;
    f16* Wf2 = Wf  + NL * DD * D4;
    f16* Kc  = Wf2 + NL * D4 * DD;
    f16* Vc  = Kc  + (size_t)NB * NL * TCAP * DD;

    const int n_w = NL * DD * D3 + NL * DD * DD + NL * DD * D4 + NL * D4 * DD;
    prep_kernel<<<(n_w + 255) / 256, 256, 0, stream>>>(qkv_w, proj_w, fc_w, fc2_w, Wq);

    gpt_loop<<<NB, 512, 0, stream>>>(
        data, r, wte_w, wte_b, wpe, ln1_w, ln1_b, ln2_w, ln2_b,
        qkv_b, proj_b, fc_b, fc2_b, lnf_w, lnf_b, head_w, head_b,
        Wq, Wp, Wf, Wf2, Kc, Vc, (float*)d_out);
}

// Round 6
// 7675.290 us; speedup vs baseline: 1.3818x; 1.1660x over previous
//
#include <hip/hip_runtime.h>
#include <math.h>

#define NB   32    // batch
#define TH   128   // scan steps
#define NL   6     // layers
#define DD   128   // model dim
#define NH   4     // heads
#define DHD  32    // head dim
#define TCAP 128   // max cached tokens
#define D3   384
#define D4   512

typedef _Float16 f16;
typedef _Float16 f16x8 __attribute__((ext_vector_type(8)));

// fp32 -> fp16 (RNE) weight conversion into workspace
__global__ void prep_kernel(const float* __restrict__ qkv, const float* __restrict__ proj,
                            const float* __restrict__ fc,  const float* __restrict__ fc2,
                            f16* __restrict__ out) {
    int i = blockIdx.x * blockDim.x + threadIdx.x;
    const int n0 = NL * DD * D3, n1 = NL * DD * DD, n2 = NL * DD * D4, n3 = NL * D4 * DD;
    const int total = n0 + n1 + n2 + n3;
    if (i >= total) return;
    float v;
    if (i < n0)                 v = qkv[i];
    else if (i < n0 + n1)       v = proj[i - n0];
    else if (i < n0 + n1 + n2)  v = fc[i - n0 - n1];
    else                        v = fc2[i - n0 - n1 - n2];
    out[i] = (f16)v;
}

// ---- DPP cross-lane reductions (VALU pipe) ------------------------------
// R5 diagnosis: __shfl_xor lowers to ds_swizzle (LDS pipe, ~40-120cy/hop);
// the 6-deep chains in LN/softmax and 3-5-deep chains in every matvec
// reduce were ~half the phase time. DPP row ops are ~4-8cy VALU ops.
template<int CTRL>
__device__ __forceinline__ float dpp_add_f(float v) {
    int t = __builtin_amdgcn_update_dpp(0, __float_as_int(v), CTRL, 0xF, 0xF, true);
    return v + __int_as_float(t);
}
template<int CTRL>
__device__ __forceinline__ float dpp_max_f(float v) {
    int iv = __float_as_int(v);
    int t = __builtin_amdgcn_update_dpp(iv, iv, CTRL, 0xF, 0xF, false);
    return fmaxf(v, __int_as_float(t));
}
// full-wave sum, result broadcast to all lanes via readlane(63)
__device__ __forceinline__ float wave_sum_bcast(float v) {
    v = dpp_add_f<0x111>(v);   // row_shr:1
    v = dpp_add_f<0x112>(v);   // row_shr:2
    v = dpp_add_f<0x114>(v);   // row_shr:4
    v = dpp_add_f<0x118>(v);   // row_shr:8  -> lane15 of each row16 has row sum
    v = dpp_add_f<0x142>(v);   // row_bcast15
    v = dpp_add_f<0x143>(v);   // row_bcast31 -> lane63 has wave sum
    return __int_as_float(__builtin_amdgcn_readlane(__float_as_int(v), 63));
}
__device__ __forceinline__ float wave_max_bcast(float v) {
    v = dpp_max_f<0x111>(v);
    v = dpp_max_f<0x112>(v);
    v = dpp_max_f<0x114>(v);
    v = dpp_max_f<0x118>(v);
    v = dpp_max_f<0x142>(v);
    v = dpp_max_f<0x143>(v);
    return __int_as_float(__builtin_amdgcn_readlane(__float_as_int(v), 63));
}
// Partial k-split reduces: row-local hops by DPP row_shl (data from lane i+N),
// cross-row hops by shfl. Results valid in the LOW consumer lanes only
// (exactly the lanes guarded by ksq==0 / ks2==0 / vjs==0).
__device__ __forceinline__ float red8_16_32(float v) {   // groups stride-8
    v = dpp_add_f<0x108>(v);   // row_shl:8
    v += __shfl_xor(v, 16);
    v += __shfl_xor(v, 32);
    return v;
}
__device__ __forceinline__ float red4_32(float v) {      // groups stride-4
    v = dpp_add_f<0x104>(v);   // row_shl:4
    v = dpp_add_f<0x108>(v);   // row_shl:8
    v += __shfl_xor(v, 16);
    v += __shfl_xor(v, 32);
    return v;
}
__device__ __forceinline__ float red2_32(float v) {      // groups stride-2
    v = dpp_add_f<0x102>(v);   // row_shl:2
    v = dpp_add_f<0x104>(v);
    v = dpp_add_f<0x108>(v);
    v += __shfl_xor(v, 16);
    v += __shfl_xor(v, 32);
    return v;
}

__device__ __forceinline__ float gelu_tanh(float v) {
    float t = v * v * v;
    return 0.5f * v * (1.f + tanhf(0.7978845608028654f * (v + 0.044715f * t)));
}

// lgkm-only barrier: orders all LDS traffic across the barrier but lets
// global (weight-prefetch) loads stay in flight.
__device__ __forceinline__ void bar_lds() {
    asm volatile("s_waitcnt lgkmcnt(0)" ::: "memory");
    __builtin_amdgcn_s_barrier();
    asm volatile("" ::: "memory");
}
// Step-boundary barrier: full drain so this step's global K/V stores are
// visible to the next step's clamped (row <= i-1) K/V reads.
__device__ __forceinline__ void bar_step() {
    asm volatile("s_waitcnt vmcnt(0) lgkmcnt(0)" ::: "memory");
    __builtin_amdgcn_s_barrier();
    asm volatile("" ::: "memory");
}

// One workgroup (512 threads) per batch element; 128 KV-cached decode steps.
// 5 lgkm-barrier phases/layer (A:qkv+LN1, B:attn, C:proj, D:fc+LN2, E:fc2).
// Weight tiles prefetched one phase ahead in HALF-TILES (32 regs each),
// issued exactly where the previous array dies (peak liveness ~115 VGPR,
// no spill at the 128 cap — R5 verified: WRITE_SIZE 26 MB).
__global__ __launch_bounds__(512, 1) void gpt_loop(
    const float* __restrict__ data,  const float* __restrict__ r,
    const float* __restrict__ wte_w, const float* __restrict__ wte_b,
    const float* __restrict__ wpe,
    const float* __restrict__ ln1_w, const float* __restrict__ ln1_b,
    const float* __restrict__ ln2_w, const float* __restrict__ ln2_b,
    const float* __restrict__ qkv_b, const float* __restrict__ proj_b,
    const float* __restrict__ fc_b,  const float* __restrict__ fc2_b,
    const float* __restrict__ lnf_w, const float* __restrict__ lnf_b,
    const float* __restrict__ head_w,const float* __restrict__ head_b,
    const f16* __restrict__ Wq, const f16* __restrict__ Wp,
    const f16* __restrict__ Wf, const f16* __restrict__ Wf2,
    f16* __restrict__ Kc, f16* __restrict__ Vc,
    float* __restrict__ Y)
{
    const int b    = blockIdx.x;
    const int tid  = threadIdx.x;
    const int lane = tid & 63;
    const int wid  = tid >> 6;

    __shared__ __align__(16) float x[DD], qv[DD], o[DD], hmid[D4];
    __shared__ __align__(16) float sc[NH][TCAP];
    __shared__ __align__(16) f16 kvK[DD], kvV[DD];   // current-step K/V row (LDS bypass)
    __shared__ __align__(16) float c_ln1w[NL][DD], c_ln1b[NL][DD], c_ln2w[NL][DD], c_ln2b[NL][DD];
    __shared__ __align__(16) float c_qkvb[NL][D3], c_projb[NL][DD], c_fcb[NL][D4], c_fc2b[NL][DD];
    __shared__ __align__(16) float c_lnfw[DD], c_lnfb[DD], c_headw[DD], c_wte0[DD], c_wte1[DD], c_wteb[DD];

    const float p0 = data[b * 2 + 0];
    const float p1 = data[b * 2 + 1];
    const float hb = head_b[0];

    f16* Kb = Kc + (size_t)b * NL * TCAP * DD;
    f16* Vb = Vc + (size_t)b * NL * TCAP * DD;

    for (int idx = tid; idx < NL * DD; idx += 512) {
        int l = idx / DD, d = idx % DD;
        c_ln1w[l][d] = ln1_w[idx]; c_ln1b[l][d] = ln1_b[idx];
        c_ln2w[l][d] = ln2_w[idx]; c_ln2b[l][d] = ln2_b[idx];
        c_projb[l][d] = proj_b[idx]; c_fc2b[l][d] = fc2_b[idx];
    }
    for (int idx = tid; idx < NL * D3; idx += 512) c_qkvb[idx / D3][idx % D3] = qkv_b[idx];
    for (int idx = tid; idx < NL * D4; idx += 512) c_fcb[idx / D4][idx % D4] = fc_b[idx];
    if (tid < DD) {
        c_lnfw[tid] = lnf_w[tid]; c_lnfb[tid] = lnf_b[tid]; c_headw[tid] = head_w[tid];
        c_wte0[tid] = wte_w[tid]; c_wte1[tid] = wte_w[DD + tid]; c_wteb[tid] = wte_b[tid];
    }
    // zero-init this block's KV cache: clamped reads of never-written rows
    // then contribute exact 0 (their softmax weight is 0 anyway).
    {
        float4 z4 = make_float4(0.f, 0.f, 0.f, 0.f);
        float4* K4 = (float4*)Kb; float4* V4 = (float4*)Vb;
        const int n4 = NL * TCAP * DD * 2 / 16;
        for (int idx = tid; idx < n4; idx += 512) { K4[idx] = z4; V4[idx] = z4; }
    }
    __syncthreads();   // full drain: zero-init complete before any KV store/read

    // ---- prologue: state + x-init for step 0 + wq(layer 0) prefetch ----
    float s_reg = 0.f;                       // state lives in wave-0 registers
    if (wid == 0) {
        float e0 = r[b * TH + 0];            // s=0, u=0 at step 0
        x[lane]      = e0 * c_wte0[lane]      + c_wteb[lane]      + wpe[lane];
        x[lane + 64] = e0 * c_wte0[lane + 64] + c_wteb[lane + 64] + wpe[64 + lane];
    }

    const int cgq = lane & 7, ksq = lane >> 3;       // qkv/fc mapping: 8 cols x 8 k-splits
    const int cbq = wid * 64 + cgq * 8, k0q = ksq * 16;
    const int cg2 = lane & 1, ks2 = lane >> 1;       // proj/fc2 mapping
    const int cb2 = (wid * 2 + cg2) * 8;
    const int hh  = wid - 4;                          // head for waves 4..7
    const int vcg = lane & 3, vjs = lane >> 2;        // AV mapping: 4 col-groups x 16 j-splits

    f16x8 wq[16];                                     // persistent: filled in E, used in A
    if (wid < 6) {
        const f16* W = Wq + cbq;
        #pragma unroll
        for (int k = 0; k < 16; k++) wq[k] = *(const f16x8*)(W + (size_t)(k0q + k) * D3);
    }
    __syncthreads();

    for (int i = 0; i < TH; i++) {
        // step-top prefetches for the head/x-init phase (held in regs all step)
        const int inext = (i + 1 < TH) ? (i + 1) : (TH - 1);
        float r_next = r[b * TH + inext];
        float wpe_a  = wpe[(i + 1) * DD + lane];
        float wpe_b  = wpe[(i + 1) * DD + 64 + lane];

        for (int l = 0; l < NL; l++) {
            f16* Krow = Kb + ((size_t)l * TCAP + i) * DD;
            f16* Vrow = Vb + ((size_t)l * TCAP + i) * DD;
            const f16* Kl = Kb + (size_t)l * TCAP * DD;
            const f16* Vl = Vb + (size_t)l * TCAP * DD;

            f16x8 wp4[4];                    // issued end-A, consumed C
            f16x8 wfh1[8], wfh2[8];          // issued end-B / mid-C, consumed D
            f16x8 wf2h1[8], wf2h2[8];        // issued mid-D, consumed E

            // ================= Phase A: LN1(inline) + qkv =================
            if (wid < 6) {
                float v0 = x[lane], v1 = x[lane + 64];
                float sm = wave_sum_bcast(v0 + v1);
                float sq = wave_sum_bcast(v0 * v0 + v1 * v1);
                float m  = sm * (1.f / DD);
                float rs = rsqrtf(sq * (1.f / DD) - m * m + 1e-5f);
                float hk[16];
                #pragma unroll
                for (int t = 0; t < 4; t++) {
                    float4 xx = *(const float4*)&x[k0q + 4 * t];
                    float4 ww = *(const float4*)&c_ln1w[l][k0q + 4 * t];
                    float4 bb = *(const float4*)&c_ln1b[l][k0q + 4 * t];
                    hk[4 * t + 0] = (xx.x - m) * rs * ww.x + bb.x;
                    hk[4 * t + 1] = (xx.y - m) * rs * ww.y + bb.y;
                    hk[4 * t + 2] = (xx.z - m) * rs * ww.z + bb.z;
                    hk[4 * t + 3] = (xx.w - m) * rs * ww.w + bb.w;
                }
                float acc[8] = {0.f,0.f,0.f,0.f,0.f,0.f,0.f,0.f};
                #pragma unroll
                for (int k = 0; k < 16; k++) {
                    f16x8 w = wq[k];
                    float hkk = hk[k];
                    #pragma unroll
                    for (int j = 0; j < 8; j++) acc[j] += hkk * (float)w[j];
                }
                #pragma unroll
                for (int j = 0; j < 8; j++) acc[j] = red8_16_32(acc[j]);
                if (ksq == 0) {
                    if (cbq < DD) {
                        #pragma unroll
                        for (int j = 0; j < 8; j++) qv[cbq + j] = acc[j] + c_qkvb[l][cbq + j];
                    } else if (cbq < 2 * DD) {
                        f16x8 kv;
                        #pragma unroll
                        for (int j = 0; j < 8; j++) kv[j] = (f16)(acc[j] + c_qkvb[l][cbq + j]);
                        *(f16x8*)(Krow + (cbq - DD)) = kv;        // for future steps
                        *(f16x8*)(&kvK[cbq - DD])   = kv;        // for THIS step (LDS)
                    } else {
                        f16x8 vv;
                        #pragma unroll
                        for (int j = 0; j < 8; j++) vv[j] = (f16)(acc[j] + c_qkvb[l][cbq + j]);
                        *(f16x8*)(Vrow + (cbq - 2 * DD)) = vv;
                        *(f16x8*)(&kvV[cbq - 2 * DD])   = vv;
                    }
                }
            }
            // wq dead -> issue wp4 for phase C (16 regs, floats across B)
            {
                const f16* W = Wp + (size_t)l * DD * DD + cb2;
                #pragma unroll
                for (int k = 0; k < 4; k++) wp4[k] = *(const f16x8*)(W + (size_t)(ks2 * 4 + k) * DD);
            }
            bar_lds();

            // ========= Phase B: attn (waves 4..7), K/V in-phase ==========
            if (wid >= 4) {
                // global K/V: rows <= i-1 only (stable since last bar_step);
                // row i comes from LDS kvK/kvV.
                const int im1 = (i > 0) ? (i - 1) : 0;
                const int j0 = (lane < i) ? lane : im1;
                const int j1 = (lane + 64 < i) ? (lane + 64) : im1;
                const f16* K0p = Kl + (size_t)j0 * DD + hh * DHD;
                const f16* K1p = Kl + (size_t)j1 * DD + hh * DHD;
                f16x8 kr0[4], kr1[4], kfr[4];
                #pragma unroll
                for (int g = 0; g < 4; g++) {
                    kr0[g] = *(const f16x8*)(K0p + g * 8);
                    kr1[g] = *(const f16x8*)(K1p + g * 8);
                }
                f16x8 vreg[8];
                const f16* Vp = Vl + hh * DHD + vcg * 8;
                #pragma unroll
                for (int t = 0; t < 8; t++) {
                    int row = vjs * 8 + t; row = (row < i) ? row : im1;
                    vreg[t] = *(const f16x8*)(Vp + (size_t)row * DD);
                }
                #pragma unroll
                for (int g = 0; g < 4; g++) kfr[g] = *(const f16x8*)(&kvK[hh * DHD + g * 8]);
                f16x8 vi = *(const f16x8*)(&kvV[hh * DHD + vcg * 8]);

                const bool ok0 = (lane <= i), ok1 = (lane + 64 <= i);
                float d0 = 0.f, d1 = 0.f;
                #pragma unroll
                for (int g = 0; g < 4; g++) {
                    f16x8 ka  = (lane      >= i) ? kfr[g] : kr0[g];
                    f16x8 kb2 = (lane + 64 >= i) ? kfr[g] : kr1[g];
                    float4 qa = *(const float4*)&qv[hh * DHD + g * 8];
                    float4 qb = *(const float4*)&qv[hh * DHD + g * 8 + 4];
                    d0 += qa.x*(float)ka[0] + qa.y*(float)ka[1] + qa.z*(float)ka[2] + qa.w*(float)ka[3]
                        + qb.x*(float)ka[4] + qb.y*(float)ka[5] + qb.z*(float)ka[6] + qb.w*(float)ka[7];
                    d1 += qa.x*(float)kb2[0] + qa.y*(float)kb2[1] + qa.z*(float)kb2[2] + qa.w*(float)kb2[3]
                        + qb.x*(float)kb2[4] + qb.y*(float)kb2[5] + qb.z*(float)kb2[6] + qb.w*(float)kb2[7];
                }
                const float sscale = 0.17677669529663687f;
                float s0 = ok0 ? d0 * sscale : -1e30f;
                float s1 = ok1 ? d1 * sscale : -1e30f;
                float mx = wave_max_bcast(fmaxf(s0, s1));
                float e0 = ok0 ? expf(s0 - mx) : 0.f;
                float e1 = ok1 ? expf(s1 - mx) : 0.f;
                float inv = 1.f / wave_sum_bcast(e0 + e1);
                sc[hh][lane]      = e0 * inv;      // rows > i get exactly 0
                sc[hh][lane + 64] = e1 * inv;
                __builtin_amdgcn_wave_barrier();   // sc write -> read, same wave
                // AV (rows > i have p == 0; row i uses vi)
                const int ja = vjs * 8;
                float4 pa = *(const float4*)&sc[hh][ja];
                float4 pb = *(const float4*)&sc[hh][ja + 4];
                float pv[8] = {pa.x, pa.y, pa.z, pa.w, pb.x, pb.y, pb.z, pb.w};
                float a[8] = {0.f,0.f,0.f,0.f,0.f,0.f,0.f,0.f};
                #pragma unroll
                for (int t = 0; t < 8; t++) {
                    f16x8 vv = (ja + t == i) ? vi : vreg[t];
                    float p = pv[t];
                    #pragma unroll
                    for (int u = 0; u < 8; u++) a[u] += p * (float)vv[u];
                }
                #pragma unroll
                for (int u = 0; u < 8; u++) a[u] = red4_32(a[u]);
                if (vjs == 0) {
                    #pragma unroll
                    for (int u = 0; u < 8; u++) o[hh * DHD + vcg * 8 + u] = a[u];
                }
            }
            // K/V regs dead -> issue wf half 1 for phase D (32 regs)
            {
                const f16* W2 = Wf + (size_t)l * DD * D4 + cbq;
                #pragma unroll
                for (int k = 0; k < 8; k++) wfh1[k] = *(const f16x8*)(W2 + (size_t)(k0q + k) * D4);
            }
            bar_lds();

            // ==== Phase C: proj + residual; issue wf half 2 after FMA ====
            {
                float4 ov = *(const float4*)&o[ks2 * 4];
                float oo[4] = {ov.x, ov.y, ov.z, ov.w};
                float acc[8] = {0.f,0.f,0.f,0.f,0.f,0.f,0.f,0.f};
                #pragma unroll
                for (int k = 0; k < 4; k++) {
                    f16x8 w = wp4[k];
                    float ok_ = oo[k];
                    #pragma unroll
                    for (int j = 0; j < 8; j++) acc[j] += ok_ * (float)w[j];
                }
                // wp4 dead -> issue wf half 2
                {
                    const f16* W2 = Wf + (size_t)l * DD * D4 + cbq;
                    #pragma unroll
                    for (int k = 0; k < 8; k++) wfh2[k] = *(const f16x8*)(W2 + (size_t)(k0q + 8 + k) * D4);
                }
                #pragma unroll
                for (int j = 0; j < 8; j++) acc[j] = red2_32(acc[j]);
                if (ks2 == 0) {
                    #pragma unroll
                    for (int j = 0; j < 8; j++) x[cb2 + j] += acc[j] + c_projb[l][cb2 + j];
                }
            }
            bar_lds();

            // == Phase D: LN2(inline) + fc + gelu; wf2 halves as wf dies ==
            {
                float v0 = x[lane], v1 = x[lane + 64];
                float sm = wave_sum_bcast(v0 + v1);
                float sq = wave_sum_bcast(v0 * v0 + v1 * v1);
                float m  = sm * (1.f / DD);
                float rs = rsqrtf(sq * (1.f / DD) - m * m + 1e-5f);
                float hk[16];
                #pragma unroll
                for (int t = 0; t < 4; t++) {
                    float4 xx = *(const float4*)&x[k0q + 4 * t];
                    float4 ww = *(const float4*)&c_ln2w[l][k0q + 4 * t];
                    float4 bb = *(const float4*)&c_ln2b[l][k0q + 4 * t];
                    hk[4 * t + 0] = (xx.x - m) * rs * ww.x + bb.x;
                    hk[4 * t + 1] = (xx.y - m) * rs * ww.y + bb.y;
                    hk[4 * t + 2] = (xx.z - m) * rs * ww.z + bb.z;
                    hk[4 * t + 3] = (xx.w - m) * rs * ww.w + bb.w;
                }
                float acc[8] = {0.f,0.f,0.f,0.f,0.f,0.f,0.f,0.f};
                #pragma unroll
                for (int k = 0; k < 8; k++) {
                    f16x8 w = wfh1[k];
                    float hkk = hk[k];
                    #pragma unroll
                    for (int j = 0; j < 8; j++) acc[j] += hkk * (float)w[j];
                }
                // wfh1 dead -> issue wf2 half 1
                {
                    const f16* W = Wf2 + (size_t)l * D4 * DD + cb2;
                    #pragma unroll
                    for (int k = 0; k < 8; k++) wf2h1[k] = *(const f16x8*)(W + (size_t)(ks2 * 16 + k) * DD);
                }
                #pragma unroll
                for (int k = 0; k < 8; k++) {
                    f16x8 w = wfh2[k];
                    float hkk = hk[8 + k];
                    #pragma unroll
                    for (int j = 0; j < 8; j++) acc[j] += hkk * (float)w[j];
                }
                // wfh2 dead -> issue wf2 half 2
                {
                    const f16* W = Wf2 + (size_t)l * D4 * DD + cb2;
                    #pragma unroll
                    for (int k = 0; k < 8; k++) wf2h2[k] = *(const f16x8*)(W + (size_t)(ks2 * 16 + 8 + k) * DD);
                }
                #pragma unroll
                for (int j = 0; j < 8; j++) acc[j] = red8_16_32(acc[j]);
                if (ksq == 0) {
                    #pragma unroll
                    for (int j = 0; j < 8; j++) hmid[cbq + j] = gelu_tanh(acc[j] + c_fcb[l][cbq + j]);
                }
            }
            bar_lds();

            // == Phase E: fc2 + residual; wq' halves as wf2 dies ==
            {
                float mk[16];
                #pragma unroll
                for (int t = 0; t < 4; t++) {
                    float4 mm = *(const float4*)&hmid[ks2 * 16 + 4 * t];
                    mk[4 * t + 0] = mm.x; mk[4 * t + 1] = mm.y;
                    mk[4 * t + 2] = mm.z; mk[4 * t + 3] = mm.w;
                }
                const int ln = (l + 1 == NL) ? 0 : (l + 1);
                float acc[8] = {0.f,0.f,0.f,0.f,0.f,0.f,0.f,0.f};
                #pragma unroll
                for (int k = 0; k < 8; k++) {
                    f16x8 w = wf2h1[k];
                    float mkk = mk[k];
                    #pragma unroll
                    for (int j = 0; j < 8; j++) acc[j] += mkk * (float)w[j];
                }
                // wf2h1 dead -> issue wq' half 1
                if (wid < 6) {
                    const f16* W = Wq + (size_t)ln * DD * D3 + cbq;
                    #pragma unroll
                    for (int k = 0; k < 8; k++) wq[k] = *(const f16x8*)(W + (size_t)(k0q + k) * D3);
                }
                #pragma unroll
                for (int k = 0; k < 8; k++) {
                    f16x8 w = wf2h2[k];
                    float mkk = mk[8 + k];
                    #pragma unroll
                    for (int j = 0; j < 8; j++) acc[j] += mkk * (float)w[j];
                }
                // wf2h2 dead -> issue wq' half 2
                if (wid < 6) {
                    const f16* W = Wq + (size_t)ln * DD * D3 + cbq;
                    #pragma unroll
                    for (int k = 0; k < 8; k++) wq[8 + k] = *(const f16x8*)(W + (size_t)(k0q + 8 + k) * D3);
                }
                #pragma unroll
                for (int j = 0; j < 8; j++) acc[j] = red2_32(acc[j]);
                if (ks2 == 0) {
                    #pragma unroll
                    for (int j = 0; j < 8; j++) x[cb2 + j] += acc[j] + c_fc2b[l][cb2 + j];
                }
            }
            bar_lds();
        } // layers

        // ==== head + state update + x-init for step i+1 (wave 0 only) ====
        if (wid == 0) {
            float v0 = x[lane], v1 = x[lane + 64];
            float sm = wave_sum_bcast(v0 + v1);
            float sq = wave_sum_bcast(v0 * v0 + v1 * v1);
            float m  = sm * (1.f / DD);
            float rs = rsqrtf(sq * (1.f / DD) - m * m + 1e-5f);
            float h0 = (v0 - m) * rs * c_lnfw[lane]      + c_lnfb[lane];
            float h1 = (v1 - m) * rs * c_lnfw[lane + 64] + c_lnfb[lane + 64];
            float v  = wave_sum_bcast(h0 * c_headw[lane] + h1 * c_headw[lane + 64]);
            float un = v + hb;
            float s  = s_reg;
            if (lane == 0) Y[b * TH + i] = s;
            float sn = s + (-p0 * s + p1 * tanhf(un));
            s_reg = sn;
            float e = r_next - sn;
            x[lane]      = e * c_wte0[lane]      + un * c_wte1[lane]      + c_wteb[lane]      + wpe_a;
            x[lane + 64] = e * c_wte0[lane + 64] + un * c_wte1[lane + 64] + c_wteb[lane + 64] + wpe_b;
        }
        bar_step();   // full vmcnt drain once per step: KV stores -> visible i+1
    } // steps
}

extern "C" void kernel_launch(void* const* d_in, const int* in_sizes, int n_in,
                              void* d_out, int out_size, void* d_ws, size_t ws_size,
                              hipStream_t stream) {
    const float* data   = (const float*)d_in[0];
    const float* r      = (const float*)d_in[1];
    const float* wte_w  = (const float*)d_in[2];
    const float* wte_b  = (const float*)d_in[3];
    const float* wpe    = (const float*)d_in[4];
    const float* ln1_w  = (const float*)d_in[5];
    const float* ln1_b  = (const float*)d_in[6];
    const float* ln2_w  = (const float*)d_in[7];
    const float* ln2_b  = (const float*)d_in[8];
    const float* qkv_w  = (const float*)d_in[9];
    const float* qkv_b  = (const float*)d_in[10];
    const float* proj_w = (const float*)d_in[11];
    const float* proj_b = (const float*)d_in[12];
    const float* fc_w   = (const float*)d_in[13];
    const float* fc_b   = (const float*)d_in[14];
    const float* fc2_w  = (const float*)d_in[15];
    const float* fc2_b  = (const float*)d_in[16];
    const float* lnf_w  = (const float*)d_in[17];
    const float* lnf_b  = (const float*)d_in[18];
    const float* head_w = (const float*)d_in[19];
    const float* head_b = (const float*)d_in[20];

    f16* wsp = (f16*)d_ws;
    f16* Wq  = wsp;
    f16* Wp  = Wq  + NL * DD * D3;
    f16* Wf  = Wp  + NL * DD * DD;
    f16* Wf2 = Wf  + NL * DD * D4;
    f16* Kc  = Wf2 + NL * D4 * DD;
    f16* Vc  = Kc  + (size_t)NB * NL * TCAP * DD;

    const int n_w = NL * DD * D3 + NL * DD * DD + NL * DD * D4 + NL * D4 * DD;
    prep_kernel<<<(n_w + 255) / 256, 256, 0, stream>>>(qkv_w, proj_w, fc_w, fc2_w, Wq);

    gpt_loop<<<NB, 512, 0, stream>>>(
        data, r, wte_w, wte_b, wpe, ln1_w, ln1_b, ln2_w, ln2_b,
        qkv_b, proj_b, fc_b, fc2_b, lnf_w, lnf_b, head_w, head_b,
        Wq, Wp, Wf, Wf2, Kc, Vc, (float*)d_out);
}

// Round 8
// 7342.673 us; speedup vs baseline: 1.4444x; 1.0453x over previous
//
#include <hip/hip_runtime.h>
#include <math.h>

#define NB   32    // batch
#define TH   128   // scan steps
#define NL   6     // layers
#define DD   128   // model dim
#define NH   4     // heads
#define DHD  32    // head dim
#define TCAP 128   // max cached tokens
#define D3   384
#define D4   512

typedef _Float16 f16;
typedef _Float16 f16x4 __attribute__((ext_vector_type(4)));
typedef _Float16 f16x8 __attribute__((ext_vector_type(8)));

// fp32 -> fp16 (RNE) weight conversion into workspace
__global__ void prep_kernel(const float* __restrict__ qkv, const float* __restrict__ proj,
                            const float* __restrict__ fc,  const float* __restrict__ fc2,
                            f16* __restrict__ out) {
    int i = blockIdx.x * blockDim.x + threadIdx.x;
    const int n0 = NL * DD * D3, n1 = NL * DD * DD, n2 = NL * DD * D4, n3 = NL * D4 * DD;
    const int total = n0 + n1 + n2 + n3;
    if (i >= total) return;
    float v;
    if (i < n0)                 v = qkv[i];
    else if (i < n0 + n1)       v = proj[i - n0];
    else if (i < n0 + n1 + n2)  v = fc[i - n0 - n1];
    else                        v = fc2[i - n0 - n1 - n2];
    out[i] = (f16)v;
}

// ---- DPP cross-lane reductions (VALU pipe, R6-verified) -----------------
template<int CTRL>
__device__ __forceinline__ float dpp_add_f(float v) {
    int t = __builtin_amdgcn_update_dpp(0, __float_as_int(v), CTRL, 0xF, 0xF, true);
    return v + __int_as_float(t);
}
template<int CTRL>
__device__ __forceinline__ float dpp_max_f(float v) {
    int iv = __float_as_int(v);
    int t = __builtin_amdgcn_update_dpp(iv, iv, CTRL, 0xF, 0xF, false);
    return fmaxf(v, __int_as_float(t));
}
__device__ __forceinline__ float wave_sum_bcast(float v) {
    v = dpp_add_f<0x111>(v); v = dpp_add_f<0x112>(v);
    v = dpp_add_f<0x114>(v); v = dpp_add_f<0x118>(v);
    v = dpp_add_f<0x142>(v); v = dpp_add_f<0x143>(v);
    return __int_as_float(__builtin_amdgcn_readlane(__float_as_int(v), 63));
}
__device__ __forceinline__ float wave_max_bcast(float v) {
    v = dpp_max_f<0x111>(v); v = dpp_max_f<0x112>(v);
    v = dpp_max_f<0x114>(v); v = dpp_max_f<0x118>(v);
    v = dpp_max_f<0x142>(v); v = dpp_max_f<0x143>(v);
    return __int_as_float(__builtin_amdgcn_readlane(__float_as_int(v), 63));
}
__device__ __forceinline__ float red8_16_32(float v) {   // stride-8 groups; valid lanes (lane&15)<8
    v = dpp_add_f<0x108>(v);
    v += __shfl_xor(v, 16);
    v += __shfl_xor(v, 32);
    return v;
}
__device__ __forceinline__ float red4_32(float v) {      // stride-4 groups; valid lanes 0-3
    v = dpp_add_f<0x104>(v);
    v = dpp_add_f<0x108>(v);
    v += __shfl_xor(v, 16);
    v += __shfl_xor(v, 32);
    return v;
}

__device__ __forceinline__ float gelu_tanh(float v) {
    float t = v * v * v;
    return 0.5f * v * (1.f + tanhf(0.7978845608028654f * (v + 0.044715f * t)));
}

// lgkm-only barrier: LDS traffic ordered; global prefetch loads stay in flight.
__device__ __forceinline__ void bar_lds() {
    asm volatile("s_waitcnt lgkmcnt(0)" ::: "memory");
    __builtin_amdgcn_s_barrier();
    asm volatile("" ::: "memory");
}
// Step-boundary barrier: full drain so K/V stores are visible next step.
__device__ __forceinline__ void bar_step() {
    asm volatile("s_waitcnt vmcnt(0) lgkmcnt(0)" ::: "memory");
    __builtin_amdgcn_s_barrier();
    asm volatile("" ::: "memory");
}

// One workgroup (512 threads) per batch element; 128 KV-cached decode steps.
// 3 lgkm-barrier phases per layer:
//   A : LN1 + qkv (waves 0-5); waves 6-7 zero the ping-pong target buffer
//   B': attn + FUSED proj-partial (waves 4-7, atomicAdd into x); 0-3 prefetch fc
//   D': LN2 + fc + gelu + FUSED fc2-partial (all waves, atomicAdd into x')
// x ping-pongs between xb[0]/xb[1] per layer so the D' adds never race the
// same-phase LN2 reads. Intra-wave redistributions (sc, o, hmid) use
// wave_barrier only — no block barrier.
__global__ __launch_bounds__(512, 1) void gpt_loop(
    const float* __restrict__ data,  const float* __restrict__ r,
    const float* __restrict__ wte_w, const float* __restrict__ wte_b,
    const float* __restrict__ wpe,
    const float* __restrict__ ln1_w, const float* __restrict__ ln1_b,
    const float* __restrict__ ln2_w, const float* __restrict__ ln2_b,
    const float* __restrict__ qkv_b, const float* __restrict__ proj_b,
    const float* __restrict__ fc_b,  const float* __restrict__ fc2_b,
    const float* __restrict__ lnf_w, const float* __restrict__ lnf_b,
    const float* __restrict__ head_w,const float* __restrict__ head_b,
    const f16* __restrict__ Wq, const f16* __restrict__ Wp,
    const f16* __restrict__ Wf, const f16* __restrict__ Wf2,
    f16* __restrict__ Kc, f16* __restrict__ Vc,
    float* __restrict__ Y)
{
    const int b    = blockIdx.x;
    const int tid  = threadIdx.x;
    const int lane = tid & 63;
    const int wid  = tid >> 6;

    __shared__ __align__(16) float xb[2][DD];
    __shared__ __align__(16) float qv[DD], o[DD], hmid[D4];
    __shared__ __align__(16) float sc[NH][TCAP];
    __shared__ __align__(16) f16 kvK[DD], kvV[DD];   // current-step K/V row (LDS bypass)
    __shared__ __align__(16) float c_ln1w[NL][DD], c_ln1b[NL][DD], c_ln2w[NL][DD], c_ln2b[NL][DD];
    __shared__ __align__(16) float c_qkvb[NL][D3], c_projb[NL][DD], c_fcb[NL][D4], c_fc2b[NL][DD];
    __shared__ __align__(16) float c_lnfw[DD], c_lnfb[DD], c_headw[DD], c_wte0[DD], c_wte1[DD], c_wteb[DD];

    const float p0 = data[b * 2 + 0];
    const float p1 = data[b * 2 + 1];
    const float hb = head_b[0];

    f16* Kb = Kc + (size_t)b * NL * TCAP * DD;
    f16* Vb = Vc + (size_t)b * NL * TCAP * DD;

    for (int idx = tid; idx < NL * DD; idx += 512) {
        int l = idx / DD, d = idx % DD;
        c_ln1w[l][d] = ln1_w[idx]; c_ln1b[l][d] = ln1_b[idx];
        c_ln2w[l][d] = ln2_w[idx]; c_ln2b[l][d] = ln2_b[idx];
        c_projb[l][d] = proj_b[idx]; c_fc2b[l][d] = fc2_b[idx];
    }
    for (int idx = tid; idx < NL * D3; idx += 512) c_qkvb[idx / D3][idx % D3] = qkv_b[idx];
    for (int idx = tid; idx < NL * D4; idx += 512) c_fcb[idx / D4][idx % D4] = fc_b[idx];
    if (tid < DD) {
        c_lnfw[tid] = lnf_w[tid]; c_lnfb[tid] = lnf_b[tid]; c_headw[tid] = head_w[tid];
        c_wte0[tid] = wte_w[tid]; c_wte1[tid] = wte_w[DD + tid]; c_wteb[tid] = wte_b[tid];
    }
    // zero-init KV cache: clamped reads of never-written rows give exact 0
    // (NaN protection: p==0 times garbage would still poison AV).
    {
        float4 z4 = make_float4(0.f, 0.f, 0.f, 0.f);
        float4* K4 = (float4*)Kb; float4* V4 = (float4*)Vb;
        const int n4 = NL * TCAP * DD * 2 / 16;
        for (int idx = tid; idx < n4; idx += 512) { K4[idx] = z4; V4[idx] = z4; }
    }
    __syncthreads();

    float s_reg = 0.f;
    if (wid == 0) {
        float e0 = r[b * TH + 0];            // s=0, u=0 at step 0
        xb[0][lane]      = e0 * c_wte0[lane]      + c_wteb[lane]      + wpe[lane];
        xb[0][lane + 64] = e0 * c_wte0[lane + 64] + c_wteb[lane + 64] + wpe[64 + lane];
    }

    const int cgq = lane & 7, ksq = lane >> 3;       // qkv/fc: 8 cols x 8 k-splits
    const int cbq = wid * 64 + cgq * 8, k0q = ksq * 16;
    const int hh  = wid - 4;                          // head for waves 4..7
    const int vcg = lane & 3, vjs = lane >> 2;        // AV: 4 col-groups x 16 j-splits
    const int pcg = lane & 31, pks = lane >> 5;       // proj partial: 32 col-grps x 2 k-splits
    const int fcg = lane & 15, fks = lane >> 4;       // fc2 partial: 16 col-grps x 4 k-splits

    f16x8 wq[16];                                     // persistent: refilled in D', used in A
    if (wid < 6) {
        const f16* W = Wq + cbq;
        #pragma unroll
        for (int k = 0; k < 16; k++) wq[k] = *(const f16x8*)(W + (size_t)(k0q + k) * D3);
    }
    __syncthreads();

    for (int i = 0; i < TH; i++) {
        const int inext = (i + 1 < TH) ? (i + 1) : (TH - 1);
        float r_next = r[b * TH + inext];
        float wpe_a  = wpe[(i + 1) * DD + lane];
        float wpe_b  = wpe[(i + 1) * DD + 64 + lane];

        for (int l = 0; l < NL; l++) {
            const int pl = l & 1;
            float* xcur = xb[pl];
            float* xnxt = xb[1 - pl];
            f16* Krow = Kb + ((size_t)l * TCAP + i) * DD;
            f16* Vrow = Vb + ((size_t)l * TCAP + i) * DD;
            const f16* Kl = Kb + (size_t)l * TCAP * DD;
            const f16* Vl = Vb + (size_t)l * TCAP * DD;

            // ================= Phase A: LN1 + qkv; zero xnxt =================
            if (wid >= 6) {
                xnxt[(wid - 6) * 64 + lane] = 0.f;   // target of D' adds
            } else {
                float v0 = xcur[lane], v1 = xcur[lane + 64];
                float sm = wave_sum_bcast(v0 + v1);
                float sq = wave_sum_bcast(v0 * v0 + v1 * v1);
                float m  = sm * (1.f / DD);
                float rs = rsqrtf(sq * (1.f / DD) - m * m + 1e-5f);
                float hk[16];
                #pragma unroll
                for (int t = 0; t < 4; t++) {
                    float4 xx = *(const float4*)&xcur[k0q + 4 * t];
                    float4 ww = *(const float4*)&c_ln1w[l][k0q + 4 * t];
                    float4 bb = *(const float4*)&c_ln1b[l][k0q + 4 * t];
                    hk[4 * t + 0] = (xx.x - m) * rs * ww.x + bb.x;
                    hk[4 * t + 1] = (xx.y - m) * rs * ww.y + bb.y;
                    hk[4 * t + 2] = (xx.z - m) * rs * ww.z + bb.z;
                    hk[4 * t + 3] = (xx.w - m) * rs * ww.w + bb.w;
                }
                float acc[8] = {0.f,0.f,0.f,0.f,0.f,0.f,0.f,0.f};
                #pragma unroll
                for (int k = 0; k < 16; k++) {
                    f16x8 w = wq[k];
                    float hkk = hk[k];
                    #pragma unroll
                    for (int j = 0; j < 8; j++) acc[j] += hkk * (float)w[j];
                }
                #pragma unroll
                for (int j = 0; j < 8; j++) acc[j] = red8_16_32(acc[j]);
                if (ksq == 0) {
                    if (cbq < DD) {
                        #pragma unroll
                        for (int j = 0; j < 8; j++) qv[cbq + j] = acc[j] + c_qkvb[l][cbq + j];
                    } else if (cbq < 2 * DD) {
                        f16x8 kv;
                        #pragma unroll
                        for (int j = 0; j < 8; j++) kv[j] = (f16)(acc[j] + c_qkvb[l][cbq + j]);
                        *(f16x8*)(Krow + (cbq - DD)) = kv;        // future steps
                        *(f16x8*)(&kvK[cbq - DD])   = kv;        // this step (LDS)
                    } else {
                        f16x8 vv;
                        #pragma unroll
                        for (int j = 0; j < 8; j++) vv[j] = (f16)(acc[j] + c_qkvb[l][cbq + j]);
                        *(f16x8*)(Vrow + (cbq - 2 * DD)) = vv;
                        *(f16x8*)(&kvV[cbq - 2 * DD])   = vv;
                    }
                }
            }
            // attn waves prefetch their proj weight tile (wq dead here)
            f16x4 wpt[16];
            if (wid >= 4) {
                const f16* W = Wp + (size_t)l * DD * DD + (size_t)(hh * DHD + pks * 16) * DD + pcg * 4;
                #pragma unroll
                for (int k = 0; k < 16; k++) wpt[k] = *(const f16x4*)(W + (size_t)k * DD);
            }
            bar_lds();

            // ====== Phase B': attn + fused proj partial (waves 4-7) ======
            f16x8 wfh1[8], wfh2[8];
            if (wid < 4) {
                const f16* W2 = Wf + (size_t)l * DD * D4 + cbq;
                #pragma unroll
                for (int k = 0; k < 8; k++) wfh1[k] = *(const f16x8*)(W2 + (size_t)(k0q + k) * D4);
                #pragma unroll
                for (int k = 0; k < 8; k++) wfh2[k] = *(const f16x8*)(W2 + (size_t)(k0q + 8 + k) * D4);
            } else {
                const int im1 = (i > 0) ? (i - 1) : 0;
                const int j0 = (lane < i) ? lane : im1;          // global rows <= i-1
                const int j1 = (lane + 64 < i) ? (lane + 64) : im1;
                const f16* K0p = Kl + (size_t)j0 * DD + hh * DHD;
                const f16* K1p = Kl + (size_t)j1 * DD + hh * DHD;
                f16x8 kr0[4], kr1[4];
                #pragma unroll
                for (int g = 0; g < 4; g++) {
                    kr0[g] = *(const f16x8*)(K0p + g * 8);
                    kr1[g] = *(const f16x8*)(K1p + g * 8);
                }
                // row i from LDS (exec-masked patch, no extra arrays)
                if (lane == i) {
                    #pragma unroll
                    for (int g = 0; g < 4; g++) kr0[g] = *(const f16x8*)(&kvK[hh * DHD + g * 8]);
                }
                if (lane + 64 == i) {
                    #pragma unroll
                    for (int g = 0; g < 4; g++) kr1[g] = *(const f16x8*)(&kvK[hh * DHD + g * 8]);
                }
                float d0 = 0.f, d1 = 0.f;
                #pragma unroll
                for (int g = 0; g < 4; g++) {
                    f16x8 ka = kr0[g], kb2 = kr1[g];
                    float4 qa = *(const float4*)&qv[hh * DHD + g * 8];
                    float4 qb = *(const float4*)&qv[hh * DHD + g * 8 + 4];
                    d0 += qa.x*(float)ka[0] + qa.y*(float)ka[1] + qa.z*(float)ka[2] + qa.w*(float)ka[3]
                        + qb.x*(float)ka[4] + qb.y*(float)ka[5] + qb.z*(float)ka[6] + qb.w*(float)ka[7];
                    d1 += qa.x*(float)kb2[0] + qa.y*(float)kb2[1] + qa.z*(float)kb2[2] + qa.w*(float)kb2[3]
                        + qb.x*(float)kb2[4] + qb.y*(float)kb2[5] + qb.z*(float)kb2[6] + qb.w*(float)kb2[7];
                }
                // V loads issued here: kr dead, latency covered by softmax
                f16x8 vreg[8];
                const f16* Vp = Vl + hh * DHD + vcg * 8;
                #pragma unroll
                for (int t = 0; t < 8; t++) {
                    int row = vjs * 8 + t; row = (row < i) ? row : im1;
                    vreg[t] = *(const f16x8*)(Vp + (size_t)row * DD);
                }
                #pragma unroll
                for (int t = 0; t < 8; t++) {
                    if (vjs * 8 + t == i) vreg[t] = *(const f16x8*)(&kvV[hh * DHD + vcg * 8]);
                }
                const float sscale = 0.17677669529663687f;
                const bool ok0 = (lane <= i), ok1 = (lane + 64 <= i);
                float s0 = ok0 ? d0 * sscale : -1e30f;
                float s1 = ok1 ? d1 * sscale : -1e30f;
                float mx = wave_max_bcast(fmaxf(s0, s1));
                float e0 = ok0 ? expf(s0 - mx) : 0.f;
                float e1 = ok1 ? expf(s1 - mx) : 0.f;
                float inv = 1.f / wave_sum_bcast(e0 + e1);
                sc[hh][lane]      = e0 * inv;      // rows > i exactly 0
                sc[hh][lane + 64] = e1 * inv;
                __builtin_amdgcn_wave_barrier();   // sc write -> read, same wave
                const int ja = vjs * 8;
                float4 pa = *(const float4*)&sc[hh][ja];
                float4 pb = *(const float4*)&sc[hh][ja + 4];
                float pv[8] = {pa.x, pa.y, pa.z, pa.w, pb.x, pb.y, pb.z, pb.w};
                float a[8] = {0.f,0.f,0.f,0.f,0.f,0.f,0.f,0.f};
                #pragma unroll
                for (int t = 0; t < 8; t++) {
                    f16x8 vv = vreg[t];
                    float p = pv[t];
                    #pragma unroll
                    for (int u = 0; u < 8; u++) a[u] += p * (float)vv[u];
                }
                #pragma unroll
                for (int u = 0; u < 8; u++) a[u] = red4_32(a[u]);
                if (vjs == 0) {
                    #pragma unroll
                    for (int u = 0; u < 8; u++) o[hh * DHD + vcg * 8 + u] = a[u];
                }
                __builtin_amdgcn_wave_barrier();   // o write -> read, same wave
                // fused proj partial: x += o_h @ Wp[h*32:+32]
                float ov[16];
                #pragma unroll
                for (int t = 0; t < 4; t++) {
                    float4 q4 = *(const float4*)&o[hh * DHD + pks * 16 + 4 * t];
                    ov[4 * t + 0] = q4.x; ov[4 * t + 1] = q4.y;
                    ov[4 * t + 2] = q4.z; ov[4 * t + 3] = q4.w;
                }
                float ap[4] = {0.f,0.f,0.f,0.f};
                #pragma unroll
                for (int k = 0; k < 16; k++) {
                    f16x4 w = wpt[k];
                    float okk = ov[k];
                    #pragma unroll
                    for (int j = 0; j < 4; j++) ap[j] += okk * (float)w[j];
                }
                #pragma unroll
                for (int j = 0; j < 4; j++) ap[j] += __shfl_xor(ap[j], 32);
                if (pks == 0) {
                    #pragma unroll
                    for (int j = 0; j < 4; j++)
                        atomicAdd(&xcur[pcg * 4 + j],
                                  ap[j] + (hh == 0 ? c_projb[l][pcg * 4 + j] : 0.f));
                }
                // K/V + wpt dead -> prefetch fc weights for D'
                const f16* W2 = Wf + (size_t)l * DD * D4 + cbq;
                #pragma unroll
                for (int k = 0; k < 8; k++) wfh1[k] = *(const f16x8*)(W2 + (size_t)(k0q + k) * D4);
                #pragma unroll
                for (int k = 0; k < 8; k++) wfh2[k] = *(const f16x8*)(W2 + (size_t)(k0q + 8 + k) * D4);
            }
            bar_lds();

            // == Phase D': LN2 + fc + gelu + fused fc2 partial (all waves) ==
            {
                float v0 = xcur[lane], v1 = xcur[lane + 64];
                float sm = wave_sum_bcast(v0 + v1);
                float sq = wave_sum_bcast(v0 * v0 + v1 * v1);
                float m  = sm * (1.f / DD);
                float rs = rsqrtf(sq * (1.f / DD) - m * m + 1e-5f);
                float hk[16];
                #pragma unroll
                for (int t = 0; t < 4; t++) {
                    float4 xx = *(const float4*)&xcur[k0q + 4 * t];
                    float4 ww = *(const float4*)&c_ln2w[l][k0q + 4 * t];
                    float4 bb = *(const float4*)&c_ln2b[l][k0q + 4 * t];
                    hk[4 * t + 0] = (xx.x - m) * rs * ww.x + bb.x;
                    hk[4 * t + 1] = (xx.y - m) * rs * ww.y + bb.y;
                    hk[4 * t + 2] = (xx.z - m) * rs * ww.z + bb.z;
                    hk[4 * t + 3] = (xx.w - m) * rs * ww.w + bb.w;
                }
                float acc[8] = {0.f,0.f,0.f,0.f,0.f,0.f,0.f,0.f};
                #pragma unroll
                for (int k = 0; k < 8; k++) {
                    f16x8 w = wfh1[k];
                    float hkk = hk[k];
                    #pragma unroll
                    for (int j = 0; j < 8; j++) acc[j] += hkk * (float)w[j];
                }
                #pragma unroll
                for (int k = 0; k < 8; k++) {
                    f16x8 w = wfh2[k];
                    float hkk = hk[8 + k];
                    #pragma unroll
                    for (int j = 0; j < 8; j++) acc[j] += hkk * (float)w[j];
                }
                // wfh dead -> issue fc2 tile; latency hidden by gelu + hmid roundtrip
                f16x8 wf2t[16];
                {
                    const f16* W3 = Wf2 + (size_t)l * D4 * DD + (size_t)(wid * 64 + fks * 16) * DD + fcg * 8;
                    #pragma unroll
                    for (int k = 0; k < 16; k++) wf2t[k] = *(const f16x8*)(W3 + (size_t)k * DD);
                }
                #pragma unroll
                for (int j = 0; j < 8; j++) acc[j] = red8_16_32(acc[j]);
                if (ksq == 0) {
                    #pragma unroll
                    for (int j = 0; j < 8; j++) hmid[cbq + j] = gelu_tanh(acc[j] + c_fcb[l][cbq + j]);
                }
                __builtin_amdgcn_wave_barrier();   // hmid write -> read, same wave
                float hv[16];
                #pragma unroll
                for (int t = 0; t < 4; t++) {
                    float4 m4 = *(const float4*)&hmid[wid * 64 + fks * 16 + 4 * t];
                    hv[4 * t + 0] = m4.x; hv[4 * t + 1] = m4.y;
                    hv[4 * t + 2] = m4.z; hv[4 * t + 3] = m4.w;
                }
                float a2[8] = {0.f,0.f,0.f,0.f,0.f,0.f,0.f,0.f};
                #pragma unroll
                for (int k = 0; k < 16; k++) {
                    f16x8 w = wf2t[k];
                    float hkk = hv[k];
                    #pragma unroll
                    for (int j = 0; j < 8; j++) a2[j] += hkk * (float)w[j];
                }
                // wf2t dead -> refill wq for next layer's phase A
                {
                    const int ln = (l + 1 == NL) ? 0 : (l + 1);
                    if (wid < 6) {
                        const f16* W = Wq + (size_t)ln * DD * D3 + cbq;
                        #pragma unroll
                        for (int k = 0; k < 16; k++) wq[k] = *(const f16x8*)(W + (size_t)(k0q + k) * D3);
                    }
                }
                #pragma unroll
                for (int j = 0; j < 8; j++) {
                    a2[j] += __shfl_xor(a2[j], 16);
                    a2[j] += __shfl_xor(a2[j], 32);
                }
                if (fks == 0) {
                    // seeded add: wave 0 carries x_old + bias into the fresh buffer
                    #pragma unroll
                    for (int j = 0; j < 8; j++)
                        atomicAdd(&xnxt[fcg * 8 + j],
                                  a2[j] + (wid == 0 ? xcur[fcg * 8 + j] + c_fc2b[l][fcg * 8 + j] : 0.f));
                }
            }
            bar_lds();
        } // layers

        // ==== head + state update + x-init for step i+1 (wave 0 only) ====
        // after 6 layers (even), current x is back in xb[0]
        if (wid == 0) {
            float v0 = xb[0][lane], v1 = xb[0][lane + 64];
            float sm = wave_sum_bcast(v0 + v1);
            float sq = wave_sum_bcast(v0 * v0 + v1 * v1);
            float m  = sm * (1.f / DD);
            float rs = rsqrtf(sq * (1.f / DD) - m * m + 1e-5f);
            float h0 = (v0 - m) * rs * c_lnfw[lane]      + c_lnfb[lane];
            float h1 = (v1 - m) * rs * c_lnfw[lane + 64] + c_lnfb[lane + 64];
            float v  = wave_sum_bcast(h0 * c_headw[lane] + h1 * c_headw[lane + 64]);
            float un = v + hb;
            float s  = s_reg;
            if (lane == 0) Y[b * TH + i] = s;
            float sn = s + (-p0 * s + p1 * tanhf(un));
            s_reg = sn;
            float e = r_next - sn;
            xb[0][lane]      = e * c_wte0[lane]      + un * c_wte1[lane]      + c_wteb[lane]      + wpe_a;
            xb[0][lane + 64] = e * c_wte0[lane + 64] + un * c_wte1[lane + 64] + c_wteb[lane + 64] + wpe_b;
        }
        bar_step();   // full vmcnt drain once per step: KV stores visible i+1
    } // steps
}

extern "C" void kernel_launch(void* const* d_in, const int* in_sizes, int n_in,
                              void* d_out, int out_size, void* d_ws, size_t ws_size,
                              hipStream_t stream) {
    const float* data   = (const float*)d_in[0];
    const float* r      = (const float*)d_in[1];
    const float* wte_w  = (const float*)d_in[2];
    const float* wte_b  = (const float*)d_in[3];
    const float* wpe    = (const float*)d_in[4];
    const float* ln1_w  = (const float*)d_in[5];
    const float* ln1_b  = (const float*)d_in[6];
    const float* ln2_w  = (const float*)d_in[7];
    const float* ln2_b  = (const float*)d_in[8];
    const float* qkv_w  = (const float*)d_in[9];
    const float* qkv_b  = (const float*)d_in[10];
    const float* proj_w = (const float*)d_in[11];
    const float* proj_b = (const float*)d_in[12];
    const float* fc_w   = (const float*)d_in[13];
    const float* fc_b   = (const float*)d_in[14];
    const float* fc2_w  = (const float*)d_in[15];
    const float* fc2_b  = (const float*)d_in[16];
    const float* lnf_w  = (const float*)d_in[17];
    const float* lnf_b  = (const float*)d_in[18];
    const float* head_w = (const float*)d_in[19];
    const float* head_b = (const float*)d_in[20];

    f16* wsp = (f16*)d_ws;
    f16* Wq  = wsp;
    f16* Wp  = Wq  + NL * DD * D3;
    f16* Wf  = Wp  + NL * DD * DD;
    f16* Wf2 = Wf  + NL * DD * D4;
    f16* Kc  = Wf2 + NL * D4 * DD;
    f16* Vc  = Kc  + (size_t)NB * NL * TCAP * DD;

    const int n_w = NL * DD * D3 + NL * DD * DD + NL * DD * D4 + NL * D4 * DD;
    prep_kernel<<<(n_w + 255) / 256, 256, 0, stream>>>(qkv_w, proj_w, fc_w, fc2_w, Wq);

    gpt_loop<<<NB, 512, 0, stream>>>(
        data, r, wte_w, wte_b, wpe, ln1_w, ln1_b, ln2_w, ln2_b,
        qkv_b, proj_b, fc_b, fc2_b, lnf_w, lnf_b, head_w, head_b,
        Wq, Wp, Wf, Wf2, Kc, Vc, (float*)d_out);
}